// Round 17
// baseline (249.938 us; speedup 1.0000x reference)
//
#include <hip/hip_runtime.h>
#include <hip/hip_fp16.h>
#include <math.h>

#define HH 480
#define WW 640
#define RAD 8
#define KK 17
#define DD 128
#define HWPIX (HH*WW)       // 307200
#define NBLK (HWPIX/256)    // 1200 exactly
#define TS 80               // x-tile width in rowsweep
#define XT 8                // tiles per row (XT*TS == WW)

static inline size_t al256(size_t x){ return (x + 255) & ~(size_t)255; }

// ================= batched counting-sort machinery (events + queries, validated v10/v12) ======
__global__ void hist_dual_kernel(const int* __restrict__ ey, const int* __restrict__ ex, int N,
                                 const int* __restrict__ qy, const int* __restrict__ qx, int M,
                                 unsigned* __restrict__ off, unsigned* __restrict__ qoff) {
    int e = blockIdx.x*blockDim.x + threadIdx.x;
    if (blockIdx.y == 0) {
        if (e < N) atomicAdd(&off[ey[e]*WW + ex[e]], 1u);
    } else {
        if (e < M) atomicAdd(&qoff[qy[e]*WW + qx[e]], 1u);
    }
}

__global__ void scan1_dual_kernel(unsigned* __restrict__ o0, unsigned* __restrict__ o1,
                                  unsigned* __restrict__ bs) {
    __shared__ unsigned sh[256];
    int t = threadIdx.x, b = blockIdx.x;
    unsigned* off = (b < NBLK) ? o0 : o1;
    int bb = (b < NBLK) ? b : b - NBLK;
    unsigned v = off[bb*256 + t];
    sh[t] = v; __syncthreads();
    for (int st = 1; st < 256; st <<= 1) {
        unsigned a = (t >= st) ? sh[t-st] : 0u;
        __syncthreads();
        sh[t] += a;
        __syncthreads();
    }
    off[bb*256 + t] = sh[t] - v;          // exclusive within block
    if (t == 255) bs[b] = sh[255];
}

// blocks 0,1: segment scans; block 2 (if do_tabs): per-dim constant tables
__global__ void scan2_dual_kernel(unsigned* __restrict__ bs_all,
                                  const float* __restrict__ Yw, const float* __restrict__ Xw,
                                  float4* __restrict__ wtab, float4* __restrict__ xtab0,
                                  float4* __restrict__ xtab1, int do_tabs) {
    if (blockIdx.x == 2) {
        if (!do_tabs) return;
        int d = threadIdx.x;
        if (d >= DD) return;
        float s, c, Yd = Yw[d];
        sincosf(-Yd, &s, &c);
        float sst, cst;
        sincosf(Yd * 0.125f, &sst, &cst);
        wtab[d] = make_float4(c, s, cst, sst);
        float th = Xw[d] * 0.125f;
        float s1, c1, s8, c8, s9, c9;
        sincosf(th, &s1, &c1);
        sincosf(8.f*th, &s8, &c8);
        sincosf(9.f*th, &s9, &c9);
        xtab0[d] = make_float4(c1, s1, c8, -s8);
        xtab1[d] = make_float4(c9, s9, 0.f, 0.f);
        return;
    }
    __shared__ unsigned sh[256];
    __shared__ unsigned carry;
    unsigned* bs = bs_all + blockIdx.x*NBLK;
    int t = threadIdx.x;
    if (t == 0) carry = 0u;
    __syncthreads();
    for (int base = 0; base < NBLK; base += 256) {
        int i = base + t;
        unsigned v = (i < NBLK) ? bs[i] : 0u;
        sh[t] = v; __syncthreads();
        for (int st = 1; st < 256; st <<= 1) {
            unsigned a = (t >= st) ? sh[t-st] : 0u;
            __syncthreads();
            sh[t] += a;
            __syncthreads();
        }
        unsigned tot = sh[255];
        if (i < NBLK) bs[i] = (sh[t] - v) + carry;
        __syncthreads();
        if (t == 0) carry += tot;
        __syncthreads();
    }
}

__global__ void scan3_dual_kernel(unsigned* __restrict__ o0, unsigned* __restrict__ o1,
                                  const unsigned* __restrict__ bs) {
    int b = blockIdx.x;
    unsigned* off = (b < NBLK) ? o0 : o1;
    int bb = (b < NBLK) ? b : b - NBLK;
    off[bb*256 + threadIdx.x] += bs[b];
}

// leaves off[pix] = END of bucket; start = pix ? off[pix-1] : 0
// main path: only tss needed (xs consumed solely by the fallback)
__global__ void sort_t_kernel(const int* __restrict__ ey, const int* __restrict__ ex,
                              const float* __restrict__ t, unsigned* __restrict__ off,
                              float* __restrict__ tss, int N) {
    int e = blockIdx.x*blockDim.x + threadIdx.x;
    if (e >= N) return;
    int pix = ey[e]*WW + ex[e];
    unsigned pos = atomicAdd(&off[pix], 1u);
    tss[pos] = t[e];
}

// fallback path: tss + xs
__global__ void sort_kernel(const int* __restrict__ ey, const int* __restrict__ ex,
                            const float* __restrict__ t, unsigned* __restrict__ off,
                            float* __restrict__ tss, int* __restrict__ xs, int N) {
    int e = blockIdx.x*blockDim.x + threadIdx.x;
    if (e >= N) return;
    int pix = ey[e]*WW + ex[e];
    unsigned pos = atomicAdd(&off[pix], 1u);
    tss[pos] = t[e];
    xs[pos]  = ex[e];
}

// slim query pixel-sort: scatter only (window count folded into query_sep, v16)
__global__ void qsort_kernel(const int* __restrict__ qy, const int* __restrict__ qx,
                             unsigned* __restrict__ qoff, unsigned* __restrict__ qidx, int M) {
    int q = blockIdx.x*blockDim.x + threadIdx.x;
    if (q >= M) return;
    int pix = qy[q]*WW + qx[q];
    unsigned pos = atomicAdd(&qoff[pix], 1u);
    qidx[pos] = q;
}

// ================= fused build+convh: sliding-DFT row sweep, 2 rows/block (v17) ==============
// H[hrow][x][dd] (packed half2) for image row hy = rb0 + hrow (zero outside image).
// Recurrence (fp32 internal): H[x+1] = e^{-i th} (H[x] - e^{-8i th} G[x-8] + e^{9i th} G[x+9])
// v17: two independent row-chains interleaved per thread -> 2x ILP on the latency-bound chain.
__global__ __launch_bounds__(128) void rowsweep_kernel(
        const unsigned* __restrict__ off, const float* __restrict__ tss,
        const float* __restrict__ Tw, const float4* __restrict__ xtab0,
        const float4* __restrict__ xtab1, __half2* __restrict__ Hout,
        int rb0, int hrows) {
    __shared__ __half2 ring[2][KK][DD];   // per-row 17-deep G history, packed (gr,gi)
    int dd    = threadIdx.x;
    int hrow0 = blockIdx.y * 2;
    int hrow1 = hrow0 + 1;
    int row1g = (hrow1 < hrows);          // row1 exists in this band's grid
    int hy0   = rb0 + hrow0;
    int hy1   = rb0 + hrow1;
    int v0    = ((unsigned)hy0 < HH);
    int v1    = row1g && ((unsigned)hy1 < HH);
    int x0    = blockIdx.x * TS;
    int x1    = x0 + TS; if (x1 > WW) x1 = WW;
    __half2* hp0 = Hout + (long long)hrow0*WW*DD + dd;
    __half2* hp1 = Hout + (long long)hrow1*WW*DD + dd;

    float Td = Tw[dd];
    float4 t0v = xtab0[dd], t1v = xtab1[dd];
    const float er_ = t0v.x,  ei_ = t0v.y;    // e^{+i th}  (init weight step)
    const float ar  = t0v.x,  ai  = -t0v.y;   // e^{-i th}  (recurrence rotation)
    const float w0r = t0v.z,  w0i = t0v.w;    // e^{-8 i th}
    const float w17r = t1v.x, w17i = t1v.y;   // e^{+9 i th}

    const int rowbase0 = hy0*WW;
    const int rowbase1 = hy1*WW;

#define GATR(valid, rowbase, col, gr, gi)                                   \
    {                                                                       \
        gr = 0.f; gi = 0.f;                                                 \
        if ((valid) && (unsigned)(col) < WW) {                              \
            int pix_ = (rowbase) + (col);                                   \
            unsigned st_ = pix_ ? off[pix_-1] : 0u;                         \
            unsigned en_ = off[pix_];                                       \
            for (unsigned p_ = st_; p_ < en_; ++p_) {                       \
                float ss_, cc_;                                             \
                __sincosf(tss[p_]*Td, &ss_, &cc_);                          \
                gr += cc_; gi += ss_;                                       \
            }                                                               \
        }                                                                   \
    }

    // init: H[x0] direct 17-tap for both rows; fill rings with G[x0-8 .. x0+8]
    float h0r = 0.f, h0i = 0.f, h1r = 0.f, h1i = 0.f;
    float wr = w0r, wi = w0i;
    #pragma unroll
    for (int j = 0; j < KK; ++j) {
        float g0r, g0i, g1r, g1i;
        GATR(v0, rowbase0, x0 + j - RAD, g0r, g0i);
        GATR(v1, rowbase1, x0 + j - RAD, g1r, g1i);
        h0r = fmaf(g0r, wr, h0r); h0r = fmaf(-g0i, wi, h0r);
        h0i = fmaf(g0r, wi, h0i); h0i = fmaf(g0i, wr, h0i);
        h1r = fmaf(g1r, wr, h1r); h1r = fmaf(-g1i, wi, h1r);
        h1i = fmaf(g1r, wi, h1i); h1i = fmaf(g1i, wr, h1i);
        ring[0][j][dd] = __floats2half2_rn(g0r, g0i);
        ring[1][j][dd] = __floats2half2_rn(g1r, g1i);
        float nr = wr*er_ - wi*ei_;
        wi       = wr*ei_ + wi*er_;
        wr       = nr;
    }
    hp0[(long long)x0*DD] = __floats2half2_rn(h0r, h0i);
    if (row1g) hp1[(long long)x0*DD] = __floats2half2_rn(h1r, h1i);

    int ri = 0;
    for (int xn = x0 + 1; xn < x1; ++xn) {
        float g0r, g0i, g1r, g1i;
        GATR(v0, rowbase0, xn + RAD, g0r, g0i);         // G[xn+8] (new), both rows
        GATR(v1, rowbase1, xn + RAD, g1r, g1i);
        float2 go0 = __half22float2(ring[0][ri][dd]);   // G[xn-9] (old)
        float2 go1 = __half22float2(ring[1][ri][dd]);
        ring[0][ri][dd] = __floats2half2_rn(g0r, g0i);
        ring[1][ri][dd] = __floats2half2_rn(g1r, g1i);
        ri = (ri + 1 == KK) ? 0 : ri + 1;
        float tr0 = h0r - (go0.x*w0r - go0.y*w0i) + (g0r*w17r - g0i*w17i);
        float ti0 = h0i - (go0.x*w0i + go0.y*w0r) + (g0r*w17i + g0i*w17r);
        float tr1 = h1r - (go1.x*w0r - go1.y*w0i) + (g1r*w17r - g1i*w17i);
        float ti1 = h1i - (go1.x*w0i + go1.y*w0r) + (g1r*w17i + g1i*w17r);
        h0r = tr0*ar - ti0*ai;
        h0i = tr0*ai + ti0*ar;
        h1r = tr1*ar - ti1*ai;
        h1i = tr1*ai + ti1*ar;
        hp0[(long long)xn*DD] = __floats2half2_rn(h0r, h0i);
        if (row1g) hp1[(long long)xn*DD] = __floats2half2_rn(h1r, h1i);
    }
#undef GATR
}

// ================= stage 2: 17-tap vertical gather; in-wave window count (validated v16) ======
__global__ __launch_bounds__(256) void query_sep_kernel(
        const unsigned* __restrict__ qidx, const int* __restrict__ qy,
        const int* __restrict__ qx, const float* __restrict__ qt,
        const float* __restrict__ Tw, const float4* __restrict__ wtab,
        const unsigned* __restrict__ H, const unsigned* __restrict__ off,
        float* __restrict__ out, int M, int r0, int band, int rb0,
        long long out_n, int real_only) {
    int lt   = threadIdx.x;
    int p    = blockIdx.x*4 + (lt >> 6);
    int lane = lt & 63;
    if (p >= M) return;
    int q = (int)qidx[p];
    int cy = qy[q];
    if (cy < r0 || cy >= r0 + band) return;
    int cx = qx[q];
    int d0 = lane*2, d1 = d0 + 1;

    // ---- in-wave window count: lanes 0..16 each handle one row (off is post-sort: END) ----
    unsigned part = 0;
    if (lane < KK) {
        int yy = cy + lane - RAD;
        if ((unsigned)yy < HH) {
            int xlo = cx - RAD; if (xlo < 0) xlo = 0;
            int xhi = cx + RAD; if (xhi > WW-1) xhi = WW-1;
            int plo = yy*WW + xlo, phi = yy*WW + xhi;
            unsigned st = plo ? off[plo-1] : 0u;
            part = off[phi] - st;
        }
    }
    for (int o = 32; o; o >>= 1) part += __shfl_down(part, o);
    float cnt = (float)__shfl(part, 0);

    float4 w0 = wtab[d0], w1 = wtab[d1];
    float wyr0 = w0.x, wyi0 = w0.y, cst0 = w0.z, sst0 = w0.w;
    float wyr1 = w1.x, wyi1 = w1.y, cst1 = w1.z, sst1 = w1.w;

    const unsigned* hp = H + ((long long)(cy - RAD - rb0)*WW + cx)*DD + d0;
    float er0 = 0.f, ei0 = 0.f, er1 = 0.f, ei1 = 0.f;
    #pragma unroll
    for (int i = 0; i < KK; ++i) {
        uint2 v = *(const uint2*)(hp + (long long)i*WW*DD);
        float2 f0 = __half22float2(*(const __half2*)&v.x);
        float2 f1 = __half22float2(*(const __half2*)&v.y);
        er0 = fmaf(f0.x, wyr0, er0); er0 = fmaf(-f0.y, wyi0, er0);
        ei0 = fmaf(f0.x, wyi0, ei0); ei0 = fmaf(f0.y, wyr0, ei0);
        er1 = fmaf(f1.x, wyr1, er1); er1 = fmaf(-f1.y, wyi1, er1);
        ei1 = fmaf(f1.x, wyi1, ei1); ei1 = fmaf(f1.y, wyr1, ei1);
        float nr;
        nr = wyr0*cst0 - wyi0*sst0; wyi0 = wyr0*sst0 + wyi0*cst0; wyr0 = nr;
        nr = wyr1*cst1 - wyi1*sst1; wyi1 = wyr1*sst1 + wyi1*cst1; wyr1 = nr;
    }

    float inv = 1.0f / fmaxf(cnt, 1.0f);
    float s, c, qtv = qt[q];
    __sincosf(qtv * Tw[d0], &s, &c);
    float outr0 = (er0*c + ei0*s) * inv, outi0 = (ei0*c - er0*s) * inv;
    __sincosf(qtv * Tw[d1], &s, &c);
    float outr1 = (er1*c + ei1*s) * inv, outi1 = (ei1*c - er1*s) * inv;

    long long base = (long long)q*DD + d0;
    if (real_only) {
        if (base + 1 < out_n) *(float2*)(out + base) = make_float2(outr0, outr1);
        else if (base < out_n) out[base] = outr0;
    } else if (2*base + 3 < out_n) {
        *(float4*)(out + 2*base) = make_float4(outr0, outi0, outr1, outi1);
    }
}

// ================= fallback: event-direct query (validated v4, 2.69 ms) =================
__global__ __launch_bounds__(256) void query_direct_kernel(
        const int* __restrict__ qy, const int* __restrict__ qx,
        const float* __restrict__ qt, const float* __restrict__ Tw,
        const float* __restrict__ Xw, const float* __restrict__ Yw,
        const unsigned* __restrict__ off, const float* __restrict__ tss,
        const int* __restrict__ xs, float* __restrict__ out,
        int M, long long out_n, int real_only) {
    __shared__ float2 swx[KK*DD];
    __shared__ float2 swy[KK*DD];
    int lt = threadIdx.x;
    for (int idx = lt; idx < KK*DD; idx += 256) {
        int j = idx / DD, dd = idx & (DD-1);
        float s, c;
        sincosf((float)(j - RAD) * 0.125f * Xw[dd], &s, &c);
        swx[idx] = make_float2(c, s);
        sincosf((float)(j - RAD) * 0.125f * Yw[dd], &s, &c);
        swy[idx] = make_float2(c, s);
    }
    __syncthreads();

    int q = blockIdx.x*2 + (lt >> 7);
    int d = lt & (DD-1);
    if (q >= M) return;

    int cy = qy[q], cx = qx[q];
    float Td = Tw[d];
    int xlo = cx - RAD; if (xlo < 0) xlo = 0;
    int xhi = cx + RAD; if (xhi > WW-1) xhi = WW-1;

    float accr = 0.f, acci = 0.f;
    unsigned cnt = 0;
    for (int i = 0; i < KK; ++i) {
        int yy = cy + i - RAD;
        if ((unsigned)yy >= HH) continue;
        int plo = yy*WW + xlo, phi = yy*WW + xhi;
        unsigned st = plo ? off[plo-1] : 0u;
        unsigned en = off[phi];
        cnt += en - st;
        float rr = 0.f, ri = 0.f;
        for (unsigned p = st; p < en; ++p) {
            float te = tss[p];
            int   xe = xs[p];
            float2 wx = swx[(xe - cx + RAD)*DD + d];
            float s, c;
            __sincosf(te * Td, &s, &c);
            rr = fmaf(c, wx.x, rr); rr = fmaf(-s, wx.y, rr);
            ri = fmaf(c, wx.y, ri); ri = fmaf(s, wx.x, ri);
        }
        float2 wy = swy[i*DD + d];
        accr = fmaf(rr, wy.x, accr); accr = fmaf(-ri, wy.y, accr);
        acci = fmaf(rr, wy.y, acci); acci = fmaf(ri, wy.x, acci);
    }

    float s, c;
    sincosf(qt[q] * Td, &s, &c);
    float inv = 1.0f / fmaxf((float)cnt, 1.0f);
    float outr = (accr*c + acci*s) * inv;
    float outi = (acci*c - accr*s) * inv;
    long long base = (long long)q*DD + d;
    if (real_only) { if (base < out_n) out[base] = outr; }
    else if (2*base + 1 < out_n) { out[2*base] = outr; out[2*base+1] = outi; }
}

extern "C" void kernel_launch(void* const* d_in, const int* in_sizes, int n_in,
                              void* d_out, int out_size, void* d_ws, size_t ws_size,
                              hipStream_t stream) {
    const float* t  = (const float*)d_in[0];
    const int*   ey = (const int*)d_in[1];
    const int*   ex = (const int*)d_in[2];
    const int*   qy = (const int*)d_in[3];
    const int*   qx = (const int*)d_in[4];
    const float* qt = (const float*)d_in[5];
    const float* Tw = (const float*)d_in[6];
    const float* Xw = (const float*)d_in[7];
    const float* Yw = (const float*)d_in[8];

    int N = in_sizes[0];
    int M = in_sizes[3];

    // ws: [off | qoff | bs(2 segs) | tss | xs | qidx | wtab | xtab0 | xtab1 | H band]
    size_t off_b  = al256((size_t)HWPIX*4);
    size_t qoff_b = al256((size_t)HWPIX*4);
    size_t bs_b   = al256((size_t)2*NBLK*4);
    size_t tss_b  = al256((size_t)N*4);
    size_t xs_b   = al256((size_t)N*4);
    size_t qidx_b = al256((size_t)M*4);
    size_t wt_b   = al256((size_t)DD*16);
    size_t xt_b   = al256((size_t)DD*16);
    size_t fixed  = off_b + qoff_b + bs_b + tss_b + xs_b + qidx_b + wt_b + 2*xt_b;
    size_t need_min = off_b + qoff_b + bs_b + tss_b + xs_b;

    if (ws_size < need_min || d_ws == nullptr) {
        hipMemsetAsync(d_out, 0, (size_t)out_size*4, stream);   // safe diagnostic
        return;
    }

    char*     ws   = (char*)d_ws;
    unsigned* off  = (unsigned*)ws;
    unsigned* qoff = (unsigned*)(ws + off_b);
    unsigned* bs   = (unsigned*)(ws + off_b + qoff_b);
    float*    tss  = (float*)(ws + off_b + qoff_b + bs_b);
    int*      xs   = (int*)(ws + off_b + qoff_b + bs_b + tss_b);
    unsigned* qidx = (unsigned*)(ws + off_b + qoff_b + bs_b + tss_b + xs_b);
    float4*   wtab = (float4*)(ws + off_b + qoff_b + bs_b + tss_b + xs_b + qidx_b);
    float4*   xtab0= (float4*)(ws + off_b + qoff_b + bs_b + tss_b + xs_b + qidx_b + wt_b);
    float4*   xtab1= (float4*)(ws + off_b + qoff_b + bs_b + tss_b + xs_b + qidx_b + wt_b + xt_b);
    __half2*  H    = (__half2*)(ws + fixed);

    long long full = (long long)M * DD;
    int real_only = (out_size < 2*full) ? 1 : 0;

    // ---- band sizing first (host arithmetic): decides which sort variant we need ----
    long long band_sz = 0;
    if (ws_size > fixed) {
        long long hrows_fit = (long long)((ws_size - fixed) / ((size_t)WW*DD*4));
        band_sz = hrows_fit - 16;
        if (band_sz > HH) band_sz = HH;
    }
    int do_tabs = (band_sz >= 32) ? 1 : 0;

    // ---- batched event+query counting sort (off and qoff adjacent: one memset) ----
    hipMemsetAsync(off, 0, off_b + (size_t)HWPIX*4, stream);
    int hb = ((N > M ? N : M) + 255)/256;
    hist_dual_kernel<<<dim3(hb, 2), 256, 0, stream>>>(ey, ex, N, qy, qx, M, off, qoff);
    scan1_dual_kernel<<<2*NBLK, 256, 0, stream>>>(off, qoff, bs);
    scan2_dual_kernel<<<3, 256, 0, stream>>>(bs, Yw, Xw, wtab, xtab0, xtab1, do_tabs);
    scan3_dual_kernel<<<2*NBLK, 256, 0, stream>>>(off, qoff, bs);

    if (!do_tabs) {
        // fallback needs xs too
        sort_kernel<<<(N+255)/256, 256, 0, stream>>>(ey, ex, t, off, tss, xs, N);
        query_direct_kernel<<<(M+1)/2, 256, 0, stream>>>(
            qy, qx, qt, Tw, Xw, Yw, off, tss, xs, (float*)d_out,
            M, (long long)out_size, real_only);
        return;
    }

    // main path: tss-only sort (xs unused downstream)
    sort_t_kernel<<<(N+255)/256, 256, 0, stream>>>(ey, ex, t, off, tss, N);

    // query pixel-sort (slim scatter; count folded into query_sep)
    qsort_kernel<<<(M+255)/256, 256, 0, stream>>>(qy, qx, qoff, qidx, M);

    // ---- banded sweep + gather ----
    for (int r0 = 0; r0 < HH; r0 += (int)band_sz) {
        int band  = (HH - r0 < band_sz) ? (HH - r0) : (int)band_sz;
        int hrows = band + 16;
        dim3 g(XT, (hrows + 1) / 2);
        rowsweep_kernel<<<g, 128, 0, stream>>>(off, tss, Tw, xtab0, xtab1, H, r0 - RAD, hrows);
        query_sep_kernel<<<(M+3)/4, 256, 0, stream>>>(
            qidx, qy, qx, qt, Tw, wtab, (const unsigned*)H, off, (float*)d_out,
            M, r0, band, r0 - RAD, (long long)out_size, real_only);
    }
}

// Round 18
// 238.216 us; speedup vs baseline: 1.0492x; 1.0492x over previous
//
#include <hip/hip_runtime.h>
#include <hip/hip_fp16.h>
#include <math.h>

#define HH 480
#define WW 640
#define RAD 8
#define KK 17
#define DD 128
#define HWPIX (HH*WW)       // 307200
#define NBLK (HWPIX/256)    // 1200 exactly
#define TS 80               // x-tile width in rowsweep
#define XT 8                // tiles per row (XT*TS == WW)
#define BANDCAP 240         // rows per band: H band 84MB -> L3-resident for query_sep

static inline size_t al256(size_t x){ return (x + 255) & ~(size_t)255; }

// ================= batched counting-sort machinery (events + queries, validated v10/v12) ======
__global__ void hist_dual_kernel(const int* __restrict__ ey, const int* __restrict__ ex, int N,
                                 const int* __restrict__ qy, const int* __restrict__ qx, int M,
                                 unsigned* __restrict__ off, unsigned* __restrict__ qoff) {
    int e = blockIdx.x*blockDim.x + threadIdx.x;
    if (blockIdx.y == 0) {
        if (e < N) atomicAdd(&off[ey[e]*WW + ex[e]], 1u);
    } else {
        if (e < M) atomicAdd(&qoff[qy[e]*WW + qx[e]], 1u);
    }
}

__global__ void scan1_dual_kernel(unsigned* __restrict__ o0, unsigned* __restrict__ o1,
                                  unsigned* __restrict__ bs) {
    __shared__ unsigned sh[256];
    int t = threadIdx.x, b = blockIdx.x;
    unsigned* off = (b < NBLK) ? o0 : o1;
    int bb = (b < NBLK) ? b : b - NBLK;
    unsigned v = off[bb*256 + t];
    sh[t] = v; __syncthreads();
    for (int st = 1; st < 256; st <<= 1) {
        unsigned a = (t >= st) ? sh[t-st] : 0u;
        __syncthreads();
        sh[t] += a;
        __syncthreads();
    }
    off[bb*256 + t] = sh[t] - v;          // exclusive within block
    if (t == 255) bs[b] = sh[255];
}

// blocks 0,1: segment scans; block 2 (if do_tabs): per-dim constant tables
__global__ void scan2_dual_kernel(unsigned* __restrict__ bs_all,
                                  const float* __restrict__ Yw, const float* __restrict__ Xw,
                                  float4* __restrict__ wtab, float4* __restrict__ xtab0,
                                  float4* __restrict__ xtab1, int do_tabs) {
    if (blockIdx.x == 2) {
        if (!do_tabs) return;
        int d = threadIdx.x;
        if (d >= DD) return;
        float s, c, Yd = Yw[d];
        sincosf(-Yd, &s, &c);
        float sst, cst;
        sincosf(Yd * 0.125f, &sst, &cst);
        wtab[d] = make_float4(c, s, cst, sst);
        float th = Xw[d] * 0.125f;
        float s1, c1, s8, c8, s9, c9;
        sincosf(th, &s1, &c1);
        sincosf(8.f*th, &s8, &c8);
        sincosf(9.f*th, &s9, &c9);
        xtab0[d] = make_float4(c1, s1, c8, -s8);
        xtab1[d] = make_float4(c9, s9, 0.f, 0.f);
        return;
    }
    __shared__ unsigned sh[256];
    __shared__ unsigned carry;
    unsigned* bs = bs_all + blockIdx.x*NBLK;
    int t = threadIdx.x;
    if (t == 0) carry = 0u;
    __syncthreads();
    for (int base = 0; base < NBLK; base += 256) {
        int i = base + t;
        unsigned v = (i < NBLK) ? bs[i] : 0u;
        sh[t] = v; __syncthreads();
        for (int st = 1; st < 256; st <<= 1) {
            unsigned a = (t >= st) ? sh[t-st] : 0u;
            __syncthreads();
            sh[t] += a;
            __syncthreads();
        }
        unsigned tot = sh[255];
        if (i < NBLK) bs[i] = (sh[t] - v) + carry;
        __syncthreads();
        if (t == 0) carry += tot;
        __syncthreads();
    }
}

__global__ void scan3_dual_kernel(unsigned* __restrict__ o0, unsigned* __restrict__ o1,
                                  const unsigned* __restrict__ bs) {
    int b = blockIdx.x;
    unsigned* off = (b < NBLK) ? o0 : o1;
    int bb = (b < NBLK) ? b : b - NBLK;
    off[bb*256 + threadIdx.x] += bs[b];
}

// main path: event sort (tss only) + query pixel-sort scatter, fused (v18)
// leaves off[pix]/qoff[pix] = END of bucket; start = pix ? off[pix-1] : 0
__global__ void sortq_dual_kernel(const int* __restrict__ ey, const int* __restrict__ ex,
                                  const float* __restrict__ t, unsigned* __restrict__ off,
                                  float* __restrict__ tss, int N,
                                  const int* __restrict__ qy, const int* __restrict__ qx,
                                  unsigned* __restrict__ qoff, unsigned* __restrict__ qidx, int M) {
    int e = blockIdx.x*blockDim.x + threadIdx.x;
    if (blockIdx.y == 0) {
        if (e < N) {
            int pix = ey[e]*WW + ex[e];
            unsigned pos = atomicAdd(&off[pix], 1u);
            tss[pos] = t[e];
        }
    } else {
        if (e < M) {
            int pix = qy[e]*WW + qx[e];
            unsigned pos = atomicAdd(&qoff[pix], 1u);
            qidx[pos] = e;
        }
    }
}

// fallback path: tss + xs
__global__ void sort_kernel(const int* __restrict__ ey, const int* __restrict__ ex,
                            const float* __restrict__ t, unsigned* __restrict__ off,
                            float* __restrict__ tss, int* __restrict__ xs, int N) {
    int e = blockIdx.x*blockDim.x + threadIdx.x;
    if (e >= N) return;
    int pix = ey[e]*WW + ex[e];
    unsigned pos = atomicAdd(&off[pix], 1u);
    tss[pos] = t[e];
    xs[pos]  = ex[e];
}

// ================= fused build+convh: sliding-DFT row sweep (validated v16 form) =============
// H[hrow][x][dd] (packed half2) for image row hy = rb0 + hrow (zero outside image).
// Recurrence (fp32 internal): H[x+1] = e^{-i th} (H[x] - e^{-8i th} G[x-8] + e^{9i th} G[x+9])
__global__ __launch_bounds__(128) void rowsweep_kernel(
        const unsigned* __restrict__ off, const float* __restrict__ tss,
        const float* __restrict__ Tw, const float4* __restrict__ xtab0,
        const float4* __restrict__ xtab1, __half2* __restrict__ Hout, int rb0) {
    __shared__ __half2 ring[KK][DD];   // 17-deep G history, packed (gr,gi)
    int dd   = threadIdx.x;
    int hrow = blockIdx.y;
    int hy   = rb0 + hrow;
    int x0   = blockIdx.x * TS;
    int x1   = x0 + TS; if (x1 > WW) x1 = WW;
    __half2* hp = Hout + (long long)hrow*WW*DD + dd;

    if ((unsigned)hy >= HH) {                       // zero-pad rows
        __half2 z = __floats2half2_rn(0.f, 0.f);
        for (int x = x0; x < x1; ++x) hp[(long long)x*DD] = z;
        return;
    }

    float Td = Tw[dd];
    float4 t0 = xtab0[dd], t1 = xtab1[dd];
    const float er_ = t0.x,  ei_ = t0.y;    // e^{+i th}  (init weight step)
    const float ar  = t0.x,  ai  = -t0.y;   // e^{-i th}  (recurrence rotation)
    const float w0r = t0.z,  w0i = t0.w;    // e^{-8 i th}
    const float w17r = t1.x, w17i = t1.y;   // e^{+9 i th}

    const int rowbase = hy*WW;
    const unsigned* offr = off + rowbase;

#define GAT(col, gr, gi)                                                    \
    {                                                                       \
        gr = 0.f; gi = 0.f;                                                 \
        if ((unsigned)(col) < WW) {                                         \
            int pix_ = rowbase + (col);                                     \
            unsigned st_ = pix_ ? off[pix_-1] : 0u;                         \
            unsigned en_ = offr[(col)];                                     \
            for (unsigned p_ = st_; p_ < en_; ++p_) {                       \
                float ss_, cc_;                                             \
                __sincosf(tss[p_]*Td, &ss_, &cc_);                          \
                gr += cc_; gi += ss_;                                       \
            }                                                               \
        }                                                                   \
    }

    // init: H[x0] direct 17-tap, fill ring with G[x0-8 .. x0+8]
    float hr = 0.f, hi = 0.f;
    float wr = w0r, wi = w0i;
    #pragma unroll
    for (int j = 0; j < KK; ++j) {
        float gr, gi; GAT(x0 + j - RAD, gr, gi);
        hr = fmaf(gr, wr, hr); hr = fmaf(-gi, wi, hr);
        hi = fmaf(gr, wi, hi); hi = fmaf(gi, wr, hi);
        ring[j][dd] = __floats2half2_rn(gr, gi);
        float nr = wr*er_ - wi*ei_;
        wi       = wr*ei_ + wi*er_;
        wr       = nr;
    }
    hp[(long long)x0*DD] = __floats2half2_rn(hr, hi);

    int ri = 0;
    for (int xn = x0 + 1; xn < x1; ++xn) {
        float gr, gi; GAT(xn + RAD, gr, gi);            // G[xn+8] (new)
        float2 go = __half22float2(ring[ri][dd]);       // G[xn-9] (old)
        ring[ri][dd] = __floats2half2_rn(gr, gi);
        ri = (ri + 1 == KK) ? 0 : ri + 1;
        float tr = hr - (go.x*w0r - go.y*w0i) + (gr*w17r - gi*w17i);
        float ti = hi - (go.x*w0i + go.y*w0r) + (gr*w17i + gi*w17r);
        hr = tr*ar - ti*ai;
        hi = tr*ai + ti*ar;
        hp[(long long)xn*DD] = __floats2half2_rn(hr, hi);
    }
#undef GAT
}

// ================= stage 2: 17-tap vertical gather; in-wave window count (validated v16) ======
__global__ __launch_bounds__(256) void query_sep_kernel(
        const unsigned* __restrict__ qidx, const int* __restrict__ qy,
        const int* __restrict__ qx, const float* __restrict__ qt,
        const float* __restrict__ Tw, const float4* __restrict__ wtab,
        const unsigned* __restrict__ H, const unsigned* __restrict__ off,
        float* __restrict__ out, int M, int r0, int band, int rb0,
        long long out_n, int real_only) {
    int lt   = threadIdx.x;
    int p    = blockIdx.x*4 + (lt >> 6);
    int lane = lt & 63;
    if (p >= M) return;
    int q = (int)qidx[p];
    int cy = qy[q];
    if (cy < r0 || cy >= r0 + band) return;
    int cx = qx[q];
    int d0 = lane*2, d1 = d0 + 1;

    // ---- in-wave window count: lanes 0..16 each handle one row (off is post-sort: END) ----
    unsigned part = 0;
    if (lane < KK) {
        int yy = cy + lane - RAD;
        if ((unsigned)yy < HH) {
            int xlo = cx - RAD; if (xlo < 0) xlo = 0;
            int xhi = cx + RAD; if (xhi > WW-1) xhi = WW-1;
            int plo = yy*WW + xlo, phi = yy*WW + xhi;
            unsigned st = plo ? off[plo-1] : 0u;
            part = off[phi] - st;
        }
    }
    for (int o = 32; o; o >>= 1) part += __shfl_down(part, o);
    float cnt = (float)__shfl(part, 0);

    float4 w0 = wtab[d0], w1 = wtab[d1];
    float wyr0 = w0.x, wyi0 = w0.y, cst0 = w0.z, sst0 = w0.w;
    float wyr1 = w1.x, wyi1 = w1.y, cst1 = w1.z, sst1 = w1.w;

    const unsigned* hp = H + ((long long)(cy - RAD - rb0)*WW + cx)*DD + d0;
    float er0 = 0.f, ei0 = 0.f, er1 = 0.f, ei1 = 0.f;
    #pragma unroll
    for (int i = 0; i < KK; ++i) {
        uint2 v = *(const uint2*)(hp + (long long)i*WW*DD);
        float2 f0 = __half22float2(*(const __half2*)&v.x);
        float2 f1 = __half22float2(*(const __half2*)&v.y);
        er0 = fmaf(f0.x, wyr0, er0); er0 = fmaf(-f0.y, wyi0, er0);
        ei0 = fmaf(f0.x, wyi0, ei0); ei0 = fmaf(f0.y, wyr0, ei0);
        er1 = fmaf(f1.x, wyr1, er1); er1 = fmaf(-f1.y, wyi1, er1);
        ei1 = fmaf(f1.x, wyi1, ei1); ei1 = fmaf(f1.y, wyr1, ei1);
        float nr;
        nr = wyr0*cst0 - wyi0*sst0; wyi0 = wyr0*sst0 + wyi0*cst0; wyr0 = nr;
        nr = wyr1*cst1 - wyi1*sst1; wyi1 = wyr1*sst1 + wyi1*cst1; wyr1 = nr;
    }

    float inv = 1.0f / fmaxf(cnt, 1.0f);
    float s, c, qtv = qt[q];
    __sincosf(qtv * Tw[d0], &s, &c);
    float outr0 = (er0*c + ei0*s) * inv, outi0 = (ei0*c - er0*s) * inv;
    __sincosf(qtv * Tw[d1], &s, &c);
    float outr1 = (er1*c + ei1*s) * inv, outi1 = (ei1*c - er1*s) * inv;

    long long base = (long long)q*DD + d0;
    if (real_only) {
        if (base + 1 < out_n) *(float2*)(out + base) = make_float2(outr0, outr1);
        else if (base < out_n) out[base] = outr0;
    } else if (2*base + 3 < out_n) {
        *(float4*)(out + 2*base) = make_float4(outr0, outi0, outr1, outi1);
    }
}

// ================= fallback: event-direct query (validated v4, 2.69 ms) =================
__global__ __launch_bounds__(256) void query_direct_kernel(
        const int* __restrict__ qy, const int* __restrict__ qx,
        const float* __restrict__ qt, const float* __restrict__ Tw,
        const float* __restrict__ Xw, const float* __restrict__ Yw,
        const unsigned* __restrict__ off, const float* __restrict__ tss,
        const int* __restrict__ xs, float* __restrict__ out,
        int M, long long out_n, int real_only) {
    __shared__ float2 swx[KK*DD];
    __shared__ float2 swy[KK*DD];
    int lt = threadIdx.x;
    for (int idx = lt; idx < KK*DD; idx += 256) {
        int j = idx / DD, dd = idx & (DD-1);
        float s, c;
        sincosf((float)(j - RAD) * 0.125f * Xw[dd], &s, &c);
        swx[idx] = make_float2(c, s);
        sincosf((float)(j - RAD) * 0.125f * Yw[dd], &s, &c);
        swy[idx] = make_float2(c, s);
    }
    __syncthreads();

    int q = blockIdx.x*2 + (lt >> 7);
    int d = lt & (DD-1);
    if (q >= M) return;

    int cy = qy[q], cx = qx[q];
    float Td = Tw[d];
    int xlo = cx - RAD; if (xlo < 0) xlo = 0;
    int xhi = cx + RAD; if (xhi > WW-1) xhi = WW-1;

    float accr = 0.f, acci = 0.f;
    unsigned cnt = 0;
    for (int i = 0; i < KK; ++i) {
        int yy = cy + i - RAD;
        if ((unsigned)yy >= HH) continue;
        int plo = yy*WW + xlo, phi = yy*WW + xhi;
        unsigned st = plo ? off[plo-1] : 0u;
        unsigned en = off[phi];
        cnt += en - st;
        float rr = 0.f, ri = 0.f;
        for (unsigned p = st; p < en; ++p) {
            float te = tss[p];
            int   xe = xs[p];
            float2 wx = swx[(xe - cx + RAD)*DD + d];
            float s, c;
            __sincosf(te * Td, &s, &c);
            rr = fmaf(c, wx.x, rr); rr = fmaf(-s, wx.y, rr);
            ri = fmaf(c, wx.y, ri); ri = fmaf(s, wx.x, ri);
        }
        float2 wy = swy[i*DD + d];
        accr = fmaf(rr, wy.x, accr); accr = fmaf(-ri, wy.y, accr);
        acci = fmaf(rr, wy.y, acci); acci = fmaf(ri, wy.x, acci);
    }

    float s, c;
    sincosf(qt[q] * Td, &s, &c);
    float inv = 1.0f / fmaxf((float)cnt, 1.0f);
    float outr = (accr*c + acci*s) * inv;
    float outi = (acci*c - accr*s) * inv;
    long long base = (long long)q*DD + d;
    if (real_only) { if (base < out_n) out[base] = outr; }
    else if (2*base + 1 < out_n) { out[2*base] = outr; out[2*base+1] = outi; }
}

extern "C" void kernel_launch(void* const* d_in, const int* in_sizes, int n_in,
                              void* d_out, int out_size, void* d_ws, size_t ws_size,
                              hipStream_t stream) {
    const float* t  = (const float*)d_in[0];
    const int*   ey = (const int*)d_in[1];
    const int*   ex = (const int*)d_in[2];
    const int*   qy = (const int*)d_in[3];
    const int*   qx = (const int*)d_in[4];
    const float* qt = (const float*)d_in[5];
    const float* Tw = (const float*)d_in[6];
    const float* Xw = (const float*)d_in[7];
    const float* Yw = (const float*)d_in[8];

    int N = in_sizes[0];
    int M = in_sizes[3];

    // ws: [off | qoff | bs(2 segs) | tss | xs | qidx | wtab | xtab0 | xtab1 | H band]
    size_t off_b  = al256((size_t)HWPIX*4);
    size_t qoff_b = al256((size_t)HWPIX*4);
    size_t bs_b   = al256((size_t)2*NBLK*4);
    size_t tss_b  = al256((size_t)N*4);
    size_t xs_b   = al256((size_t)N*4);
    size_t qidx_b = al256((size_t)M*4);
    size_t wt_b   = al256((size_t)DD*16);
    size_t xt_b   = al256((size_t)DD*16);
    size_t fixed  = off_b + qoff_b + bs_b + tss_b + xs_b + qidx_b + wt_b + 2*xt_b;
    size_t need_min = off_b + qoff_b + bs_b + tss_b + xs_b;

    if (ws_size < need_min || d_ws == nullptr) {
        hipMemsetAsync(d_out, 0, (size_t)out_size*4, stream);   // safe diagnostic
        return;
    }

    char*     ws   = (char*)d_ws;
    unsigned* off  = (unsigned*)ws;
    unsigned* qoff = (unsigned*)(ws + off_b);
    unsigned* bs   = (unsigned*)(ws + off_b + qoff_b);
    float*    tss  = (float*)(ws + off_b + qoff_b + bs_b);
    int*      xs   = (int*)(ws + off_b + qoff_b + bs_b + tss_b);
    unsigned* qidx = (unsigned*)(ws + off_b + qoff_b + bs_b + tss_b + xs_b);
    float4*   wtab = (float4*)(ws + off_b + qoff_b + bs_b + tss_b + xs_b + qidx_b);
    float4*   xtab0= (float4*)(ws + off_b + qoff_b + bs_b + tss_b + xs_b + qidx_b + wt_b);
    float4*   xtab1= (float4*)(ws + off_b + qoff_b + bs_b + tss_b + xs_b + qidx_b + wt_b + xt_b);
    __half2*  H    = (__half2*)(ws + fixed);

    long long full = (long long)M * DD;
    int real_only = (out_size < 2*full) ? 1 : 0;

    // ---- band sizing first (host arithmetic): decides which sort variant we need ----
    long long band_sz = 0;
    if (ws_size > fixed) {
        long long hrows_fit = (long long)((ws_size - fixed) / ((size_t)WW*DD*4));
        band_sz = hrows_fit - 16;
        if (band_sz > HH) band_sz = HH;
    }
    int do_tabs = (band_sz >= 32) ? 1 : 0;
    if (band_sz > BANDCAP) band_sz = BANDCAP;   // v18: cap band so H band (~84MB) stays L3-hot

    // ---- batched event+query counting sort (off and qoff adjacent: one memset) ----
    hipMemsetAsync(off, 0, off_b + (size_t)HWPIX*4, stream);
    int hb = ((N > M ? N : M) + 255)/256;
    hist_dual_kernel<<<dim3(hb, 2), 256, 0, stream>>>(ey, ex, N, qy, qx, M, off, qoff);
    scan1_dual_kernel<<<2*NBLK, 256, 0, stream>>>(off, qoff, bs);
    scan2_dual_kernel<<<3, 256, 0, stream>>>(bs, Yw, Xw, wtab, xtab0, xtab1, do_tabs);
    scan3_dual_kernel<<<2*NBLK, 256, 0, stream>>>(off, qoff, bs);

    if (!do_tabs) {
        // fallback needs xs too
        sort_kernel<<<(N+255)/256, 256, 0, stream>>>(ey, ex, t, off, tss, xs, N);
        query_direct_kernel<<<(M+1)/2, 256, 0, stream>>>(
            qy, qx, qt, Tw, Xw, Yw, off, tss, xs, (float*)d_out,
            M, (long long)out_size, real_only);
        return;
    }

    // main path: fused event sort (tss only) + query pixel-sort scatter
    sortq_dual_kernel<<<dim3(hb, 2), 256, 0, stream>>>(ey, ex, t, off, tss, N,
                                                       qy, qx, qoff, qidx, M);

    // ---- banded sweep + gather ----
    for (int r0 = 0; r0 < HH; r0 += (int)band_sz) {
        int band  = (HH - r0 < band_sz) ? (HH - r0) : (int)band_sz;
        int hrows = band + 16;
        dim3 g(XT, hrows);
        rowsweep_kernel<<<g, 128, 0, stream>>>(off, tss, Tw, xtab0, xtab1, H, r0 - RAD);
        query_sep_kernel<<<(M+3)/4, 256, 0, stream>>>(
            qidx, qy, qx, qt, Tw, wtab, (const unsigned*)H, off, (float*)d_out,
            M, r0, band, r0 - RAD, (long long)out_size, real_only);
    }
}

// Round 19
// 224.357 us; speedup vs baseline: 1.1140x; 1.0618x over previous
//
#include <hip/hip_runtime.h>
#include <hip/hip_fp16.h>
#include <math.h>

#define HH 480
#define WW 640
#define RAD 8
#define KK 17
#define DD 128
#define HWPIX (HH*WW)       // 307200
#define NBLK (HWPIX/256)    // 1200 exactly
#define TS 80               // x-tile width in rowsweep
#define XT 8                // tiles per row (XT*TS == WW)
#define QBINS (HH*8)        // 3840 coarse query bins: qy*8 + qx/80
#define QBX 80              // x bin width (WW/8)

static inline size_t al256(size_t x){ return (x + 255) & ~(size_t)255; }

// ================= counting-sort machinery: events (pixel bins) + queries (coarse bins) ======
__global__ void hist_dual_kernel(const int* __restrict__ ey, const int* __restrict__ ex, int N,
                                 const int* __restrict__ qy, const int* __restrict__ qx, int M,
                                 unsigned* __restrict__ off, unsigned* __restrict__ qbin) {
    int e = blockIdx.x*blockDim.x + threadIdx.x;
    if (blockIdx.y == 0) {
        if (e < N) atomicAdd(&off[ey[e]*WW + ex[e]], 1u);
    } else {
        if (e < M) atomicAdd(&qbin[qy[e]*8 + qx[e]/QBX], 1u);
    }
}

__global__ void scan1_kernel(unsigned* __restrict__ off, unsigned* __restrict__ bs) {
    __shared__ unsigned sh[256];
    int t = threadIdx.x, b = blockIdx.x;
    unsigned v = off[b*256 + t];
    sh[t] = v; __syncthreads();
    for (int st = 1; st < 256; st <<= 1) {
        unsigned a = (t >= st) ? sh[t-st] : 0u;
        __syncthreads();
        sh[t] += a;
        __syncthreads();
    }
    off[b*256 + t] = sh[t] - v;          // exclusive within block
    if (t == 255) bs[b] = sh[255];
}

// block 0: event block-sum scan; block 1: coarse qbin scan (in place); block 2: const tables
__global__ void scan2_dual_kernel(unsigned* __restrict__ bs, unsigned* __restrict__ qbin,
                                  const float* __restrict__ Yw, const float* __restrict__ Xw,
                                  float4* __restrict__ wtab, float4* __restrict__ xtab0,
                                  float4* __restrict__ xtab1, int do_tabs) {
    if (blockIdx.x == 2) {
        if (!do_tabs) return;
        int d = threadIdx.x;
        if (d >= DD) return;
        float s, c, Yd = Yw[d];
        sincosf(-Yd, &s, &c);
        float sst, cst;
        sincosf(Yd * 0.125f, &sst, &cst);
        wtab[d] = make_float4(c, s, cst, sst);
        float th = Xw[d] * 0.125f;
        float s1, c1, s8, c8, s9, c9;
        sincosf(th, &s1, &c1);
        sincosf(8.f*th, &s8, &c8);
        sincosf(9.f*th, &s9, &c9);
        xtab0[d] = make_float4(c1, s1, c8, -s8);
        xtab1[d] = make_float4(c9, s9, 0.f, 0.f);
        return;
    }
    __shared__ unsigned sh[256];
    __shared__ unsigned carry;
    unsigned* arr = (blockIdx.x == 0) ? bs : qbin;
    int n         = (blockIdx.x == 0) ? NBLK : QBINS;
    int t = threadIdx.x;
    if (t == 0) carry = 0u;
    __syncthreads();
    for (int base = 0; base < n; base += 256) {
        int i = base + t;
        unsigned v = (i < n) ? arr[i] : 0u;
        sh[t] = v; __syncthreads();
        for (int st = 1; st < 256; st <<= 1) {
            unsigned a = (t >= st) ? sh[t-st] : 0u;
            __syncthreads();
            sh[t] += a;
            __syncthreads();
        }
        unsigned tot = sh[255];
        if (i < n) arr[i] = (sh[t] - v) + carry;
        __syncthreads();
        if (t == 0) carry += tot;
        __syncthreads();
    }
}

__global__ void scan3_kernel(unsigned* __restrict__ off, const unsigned* __restrict__ bs) {
    off[blockIdx.x*256 + threadIdx.x] += bs[blockIdx.x];
}

// main path: event sort (tss only) + coarse query scatter, fused
// leaves off[pix] = END of bucket; start = pix ? off[pix-1] : 0
__global__ void sortq_dual_kernel(const int* __restrict__ ey, const int* __restrict__ ex,
                                  const float* __restrict__ t, unsigned* __restrict__ off,
                                  float* __restrict__ tss, int N,
                                  const int* __restrict__ qy, const int* __restrict__ qx,
                                  unsigned* __restrict__ qbin, unsigned* __restrict__ qidx, int M) {
    int e = blockIdx.x*blockDim.x + threadIdx.x;
    if (blockIdx.y == 0) {
        if (e < N) {
            int pix = ey[e]*WW + ex[e];
            unsigned pos = atomicAdd(&off[pix], 1u);
            tss[pos] = t[e];
        }
    } else {
        if (e < M) {
            int bin = qy[e]*8 + qx[e]/QBX;
            unsigned pos = atomicAdd(&qbin[bin], 1u);
            qidx[pos] = e;
        }
    }
}

// fallback path: tss + xs
__global__ void sort_kernel(const int* __restrict__ ey, const int* __restrict__ ex,
                            const float* __restrict__ t, unsigned* __restrict__ off,
                            float* __restrict__ tss, int* __restrict__ xs, int N) {
    int e = blockIdx.x*blockDim.x + threadIdx.x;
    if (e >= N) return;
    int pix = ey[e]*WW + ex[e];
    unsigned pos = atomicAdd(&off[pix], 1u);
    tss[pos] = t[e];
    xs[pos]  = ex[e];
}

// ================= fused build+convh: sliding-DFT row sweep (validated v16 form) =============
// H[hrow][x][dd] (packed half2) for image row hy = rb0 + hrow (zero outside image).
// Recurrence (fp32 internal): H[x+1] = e^{-i th} (H[x] - e^{-8i th} G[x-8] + e^{9i th} G[x+9])
__global__ __launch_bounds__(128) void rowsweep_kernel(
        const unsigned* __restrict__ off, const float* __restrict__ tss,
        const float* __restrict__ Tw, const float4* __restrict__ xtab0,
        const float4* __restrict__ xtab1, __half2* __restrict__ Hout, int rb0) {
    __shared__ __half2 ring[KK][DD];   // 17-deep G history, packed (gr,gi)
    int dd   = threadIdx.x;
    int hrow = blockIdx.y;
    int hy   = rb0 + hrow;
    int x0   = blockIdx.x * TS;
    int x1   = x0 + TS; if (x1 > WW) x1 = WW;
    __half2* hp = Hout + (long long)hrow*WW*DD + dd;

    if ((unsigned)hy >= HH) {                       // zero-pad rows
        __half2 z = __floats2half2_rn(0.f, 0.f);
        for (int x = x0; x < x1; ++x) hp[(long long)x*DD] = z;
        return;
    }

    float Td = Tw[dd];
    float4 t0 = xtab0[dd], t1 = xtab1[dd];
    const float er_ = t0.x,  ei_ = t0.y;    // e^{+i th}  (init weight step)
    const float ar  = t0.x,  ai  = -t0.y;   // e^{-i th}  (recurrence rotation)
    const float w0r = t0.z,  w0i = t0.w;    // e^{-8 i th}
    const float w17r = t1.x, w17i = t1.y;   // e^{+9 i th}

    const int rowbase = hy*WW;
    const unsigned* offr = off + rowbase;

#define GAT(col, gr, gi)                                                    \
    {                                                                       \
        gr = 0.f; gi = 0.f;                                                 \
        if ((unsigned)(col) < WW) {                                         \
            int pix_ = rowbase + (col);                                     \
            unsigned st_ = pix_ ? off[pix_-1] : 0u;                         \
            unsigned en_ = offr[(col)];                                     \
            for (unsigned p_ = st_; p_ < en_; ++p_) {                       \
                float ss_, cc_;                                             \
                __sincosf(tss[p_]*Td, &ss_, &cc_);                          \
                gr += cc_; gi += ss_;                                       \
            }                                                               \
        }                                                                   \
    }

    // init: H[x0] direct 17-tap, fill ring with G[x0-8 .. x0+8]
    float hr = 0.f, hi = 0.f;
    float wr = w0r, wi = w0i;
    #pragma unroll
    for (int j = 0; j < KK; ++j) {
        float gr, gi; GAT(x0 + j - RAD, gr, gi);
        hr = fmaf(gr, wr, hr); hr = fmaf(-gi, wi, hr);
        hi = fmaf(gr, wi, hi); hi = fmaf(gi, wr, hi);
        ring[j][dd] = __floats2half2_rn(gr, gi);
        float nr = wr*er_ - wi*ei_;
        wi       = wr*ei_ + wi*er_;
        wr       = nr;
    }
    hp[(long long)x0*DD] = __floats2half2_rn(hr, hi);

    int ri = 0;
    for (int xn = x0 + 1; xn < x1; ++xn) {
        float gr, gi; GAT(xn + RAD, gr, gi);            // G[xn+8] (new)
        float2 go = __half22float2(ring[ri][dd]);       // G[xn-9] (old)
        ring[ri][dd] = __floats2half2_rn(gr, gi);
        ri = (ri + 1 == KK) ? 0 : ri + 1;
        float tr = hr - (go.x*w0r - go.y*w0i) + (gr*w17r - gi*w17i);
        float ti = hi - (go.x*w0i + go.y*w0r) + (gr*w17i + gi*w17r);
        hr = tr*ar - ti*ai;
        hi = tr*ai + ti*ar;
        hp[(long long)xn*DD] = __floats2half2_rn(hr, hi);
    }
#undef GAT
}

// ================= stage 2: 17-tap vertical gather; in-wave window count (validated v16) ======
__global__ __launch_bounds__(256) void query_sep_kernel(
        const unsigned* __restrict__ qidx, const int* __restrict__ qy,
        const int* __restrict__ qx, const float* __restrict__ qt,
        const float* __restrict__ Tw, const float4* __restrict__ wtab,
        const unsigned* __restrict__ H, const unsigned* __restrict__ off,
        float* __restrict__ out, int M, int r0, int band, int rb0,
        long long out_n, int real_only) {
    int lt   = threadIdx.x;
    int p    = blockIdx.x*4 + (lt >> 6);
    int lane = lt & 63;
    if (p >= M) return;
    int q = (int)qidx[p];
    int cy = qy[q];
    if (cy < r0 || cy >= r0 + band) return;
    int cx = qx[q];
    int d0 = lane*2, d1 = d0 + 1;

    // ---- in-wave window count: lanes 0..16 each handle one row (off is post-sort: END) ----
    unsigned part = 0;
    if (lane < KK) {
        int yy = cy + lane - RAD;
        if ((unsigned)yy < HH) {
            int xlo = cx - RAD; if (xlo < 0) xlo = 0;
            int xhi = cx + RAD; if (xhi > WW-1) xhi = WW-1;
            int plo = yy*WW + xlo, phi = yy*WW + xhi;
            unsigned st = plo ? off[plo-1] : 0u;
            part = off[phi] - st;
        }
    }
    for (int o = 32; o; o >>= 1) part += __shfl_down(part, o);
    float cnt = (float)__shfl(part, 0);

    float4 w0 = wtab[d0], w1 = wtab[d1];
    float wyr0 = w0.x, wyi0 = w0.y, cst0 = w0.z, sst0 = w0.w;
    float wyr1 = w1.x, wyi1 = w1.y, cst1 = w1.z, sst1 = w1.w;

    const unsigned* hp = H + ((long long)(cy - RAD - rb0)*WW + cx)*DD + d0;
    float er0 = 0.f, ei0 = 0.f, er1 = 0.f, ei1 = 0.f;
    #pragma unroll
    for (int i = 0; i < KK; ++i) {
        uint2 v = *(const uint2*)(hp + (long long)i*WW*DD);
        float2 f0 = __half22float2(*(const __half2*)&v.x);
        float2 f1 = __half22float2(*(const __half2*)&v.y);
        er0 = fmaf(f0.x, wyr0, er0); er0 = fmaf(-f0.y, wyi0, er0);
        ei0 = fmaf(f0.x, wyi0, ei0); ei0 = fmaf(f0.y, wyr0, ei0);
        er1 = fmaf(f1.x, wyr1, er1); er1 = fmaf(-f1.y, wyi1, er1);
        ei1 = fmaf(f1.x, wyi1, ei1); ei1 = fmaf(f1.y, wyr1, ei1);
        float nr;
        nr = wyr0*cst0 - wyi0*sst0; wyi0 = wyr0*sst0 + wyi0*cst0; wyr0 = nr;
        nr = wyr1*cst1 - wyi1*sst1; wyi1 = wyr1*sst1 + wyi1*cst1; wyr1 = nr;
    }

    float inv = 1.0f / fmaxf(cnt, 1.0f);
    float s, c, qtv = qt[q];
    __sincosf(qtv * Tw[d0], &s, &c);
    float outr0 = (er0*c + ei0*s) * inv, outi0 = (ei0*c - er0*s) * inv;
    __sincosf(qtv * Tw[d1], &s, &c);
    float outr1 = (er1*c + ei1*s) * inv, outi1 = (ei1*c - er1*s) * inv;

    long long base = (long long)q*DD + d0;
    if (real_only) {
        if (base + 1 < out_n) *(float2*)(out + base) = make_float2(outr0, outr1);
        else if (base < out_n) out[base] = outr0;
    } else if (2*base + 3 < out_n) {
        *(float4*)(out + 2*base) = make_float4(outr0, outi0, outr1, outi1);
    }
}

// ================= fallback: event-direct query (validated v4, 2.69 ms) =================
__global__ __launch_bounds__(256) void query_direct_kernel(
        const int* __restrict__ qy, const int* __restrict__ qx,
        const float* __restrict__ qt, const float* __restrict__ Tw,
        const float* __restrict__ Xw, const float* __restrict__ Yw,
        const unsigned* __restrict__ off, const float* __restrict__ tss,
        const int* __restrict__ xs, float* __restrict__ out,
        int M, long long out_n, int real_only) {
    __shared__ float2 swx[KK*DD];
    __shared__ float2 swy[KK*DD];
    int lt = threadIdx.x;
    for (int idx = lt; idx < KK*DD; idx += 256) {
        int j = idx / DD, dd = idx & (DD-1);
        float s, c;
        sincosf((float)(j - RAD) * 0.125f * Xw[dd], &s, &c);
        swx[idx] = make_float2(c, s);
        sincosf((float)(j - RAD) * 0.125f * Yw[dd], &s, &c);
        swy[idx] = make_float2(c, s);
    }
    __syncthreads();

    int q = blockIdx.x*2 + (lt >> 7);
    int d = lt & (DD-1);
    if (q >= M) return;

    int cy = qy[q], cx = qx[q];
    float Td = Tw[d];
    int xlo = cx - RAD; if (xlo < 0) xlo = 0;
    int xhi = cx + RAD; if (xhi > WW-1) xhi = WW-1;

    float accr = 0.f, acci = 0.f;
    unsigned cnt = 0;
    for (int i = 0; i < KK; ++i) {
        int yy = cy + i - RAD;
        if ((unsigned)yy >= HH) continue;
        int plo = yy*WW + xlo, phi = yy*WW + xhi;
        unsigned st = plo ? off[plo-1] : 0u;
        unsigned en = off[phi];
        cnt += en - st;
        float rr = 0.f, ri = 0.f;
        for (unsigned p = st; p < en; ++p) {
            float te = tss[p];
            int   xe = xs[p];
            float2 wx = swx[(xe - cx + RAD)*DD + d];
            float s, c;
            __sincosf(te * Td, &s, &c);
            rr = fmaf(c, wx.x, rr); rr = fmaf(-s, wx.y, rr);
            ri = fmaf(c, wx.y, ri); ri = fmaf(s, wx.x, ri);
        }
        float2 wy = swy[i*DD + d];
        accr = fmaf(rr, wy.x, accr); accr = fmaf(-ri, wy.y, accr);
        acci = fmaf(rr, wy.y, acci); acci = fmaf(ri, wy.x, acci);
    }

    float s, c;
    sincosf(qt[q] * Td, &s, &c);
    float inv = 1.0f / fmaxf((float)cnt, 1.0f);
    float outr = (accr*c + acci*s) * inv;
    float outi = (acci*c - accr*s) * inv;
    long long base = (long long)q*DD + d;
    if (real_only) { if (base < out_n) out[base] = outr; }
    else if (2*base + 1 < out_n) { out[2*base] = outr; out[2*base+1] = outi; }
}

extern "C" void kernel_launch(void* const* d_in, const int* in_sizes, int n_in,
                              void* d_out, int out_size, void* d_ws, size_t ws_size,
                              hipStream_t stream) {
    const float* t  = (const float*)d_in[0];
    const int*   ey = (const int*)d_in[1];
    const int*   ex = (const int*)d_in[2];
    const int*   qy = (const int*)d_in[3];
    const int*   qx = (const int*)d_in[4];
    const float* qt = (const float*)d_in[5];
    const float* Tw = (const float*)d_in[6];
    const float* Xw = (const float*)d_in[7];
    const float* Yw = (const float*)d_in[8];

    int N = in_sizes[0];
    int M = in_sizes[3];

    // ws: [off | qbin | bs | tss | xs | qidx | wtab | xtab0 | xtab1 | H band]
    size_t off_b  = al256((size_t)HWPIX*4);
    size_t qbin_b = al256((size_t)QBINS*4);
    size_t bs_b   = al256((size_t)NBLK*4);
    size_t tss_b  = al256((size_t)N*4);
    size_t xs_b   = al256((size_t)N*4);
    size_t qidx_b = al256((size_t)M*4);
    size_t wt_b   = al256((size_t)DD*16);
    size_t xt_b   = al256((size_t)DD*16);
    size_t fixed  = off_b + qbin_b + bs_b + tss_b + xs_b + qidx_b + wt_b + 2*xt_b;
    size_t need_min = off_b + qbin_b + bs_b + tss_b + xs_b;

    if (ws_size < need_min || d_ws == nullptr) {
        hipMemsetAsync(d_out, 0, (size_t)out_size*4, stream);   // safe diagnostic
        return;
    }

    char*     ws   = (char*)d_ws;
    unsigned* off  = (unsigned*)ws;
    unsigned* qbin = (unsigned*)(ws + off_b);
    unsigned* bs   = (unsigned*)(ws + off_b + qbin_b);
    float*    tss  = (float*)(ws + off_b + qbin_b + bs_b);
    int*      xs   = (int*)(ws + off_b + qbin_b + bs_b + tss_b);
    unsigned* qidx = (unsigned*)(ws + off_b + qbin_b + bs_b + tss_b + xs_b);
    float4*   wtab = (float4*)(ws + off_b + qbin_b + bs_b + tss_b + xs_b + qidx_b);
    float4*   xtab0= (float4*)(ws + off_b + qbin_b + bs_b + tss_b + xs_b + qidx_b + wt_b);
    float4*   xtab1= (float4*)(ws + off_b + qbin_b + bs_b + tss_b + xs_b + qidx_b + wt_b + xt_b);
    __half2*  H    = (__half2*)(ws + fixed);

    long long full = (long long)M * DD;
    int real_only = (out_size < 2*full) ? 1 : 0;

    // ---- band sizing first (host arithmetic): decides which sort variant we need ----
    long long band_sz = 0;
    if (ws_size > fixed) {
        long long hrows_fit = (long long)((ws_size - fixed) / ((size_t)WW*DD*4));
        band_sz = hrows_fit - 16;
        if (band_sz > HH) band_sz = HH;
    }
    int do_tabs = (band_sz >= 32) ? 1 : 0;

    // ---- event counting sort + coarse query binning (off and qbin adjacent: one memset) ----
    hipMemsetAsync(off, 0, off_b + qbin_b, stream);
    int hb = ((N > M ? N : M) + 255)/256;
    hist_dual_kernel<<<dim3(hb, 2), 256, 0, stream>>>(ey, ex, N, qy, qx, M, off, qbin);
    scan1_kernel<<<NBLK, 256, 0, stream>>>(off, bs);
    scan2_dual_kernel<<<3, 256, 0, stream>>>(bs, qbin, Yw, Xw, wtab, xtab0, xtab1, do_tabs);
    scan3_kernel<<<NBLK, 256, 0, stream>>>(off, bs);

    if (!do_tabs) {
        // fallback needs xs too
        sort_kernel<<<(N+255)/256, 256, 0, stream>>>(ey, ex, t, off, tss, xs, N);
        query_direct_kernel<<<(M+1)/2, 256, 0, stream>>>(
            qy, qx, qt, Tw, Xw, Yw, off, tss, xs, (float*)d_out,
            M, (long long)out_size, real_only);
        return;
    }

    // main path: fused event sort (tss only) + coarse query scatter
    sortq_dual_kernel<<<dim3(hb, 2), 256, 0, stream>>>(ey, ex, t, off, tss, N,
                                                       qy, qx, qbin, qidx, M);

    // ---- banded sweep + gather (single band when ws allows) ----
    for (int r0 = 0; r0 < HH; r0 += (int)band_sz) {
        int band  = (HH - r0 < band_sz) ? (HH - r0) : (int)band_sz;
        int hrows = band + 16;
        dim3 g(XT, hrows);
        rowsweep_kernel<<<g, 128, 0, stream>>>(off, tss, Tw, xtab0, xtab1, H, r0 - RAD);
        query_sep_kernel<<<(M+3)/4, 256, 0, stream>>>(
            qidx, qy, qx, qt, Tw, wtab, (const unsigned*)H, off, (float*)d_out,
            M, r0, band, r0 - RAD, (long long)out_size, real_only);
    }
}

// Round 20
// 209.949 us; speedup vs baseline: 1.1905x; 1.0686x over previous
//
#include <hip/hip_runtime.h>
#include <hip/hip_fp16.h>
#include <math.h>

#define HH 480
#define WW 640
#define RAD 8
#define KK 17
#define DD 128
#define HWPIX (HH*WW)       // 307200
#define NBLK (HWPIX/256)    // 1200 exactly
#define TS 80               // x-tile width in rowsweep
#define XT 8                // tiles per row (XT*TS == WW)

static inline size_t al256(size_t x){ return (x + 255) & ~(size_t)255; }

// ================= batched counting-sort machinery (events + queries, validated v10/v12) ======
__global__ void hist_dual_kernel(const int* __restrict__ ey, const int* __restrict__ ex, int N,
                                 const int* __restrict__ qy, const int* __restrict__ qx, int M,
                                 unsigned* __restrict__ off, unsigned* __restrict__ qoff) {
    int e = blockIdx.x*blockDim.x + threadIdx.x;
    if (blockIdx.y == 0) {
        if (e < N) atomicAdd(&off[ey[e]*WW + ex[e]], 1u);
    } else {
        if (e < M) atomicAdd(&qoff[qy[e]*WW + qx[e]], 1u);
    }
}

__global__ void scan1_dual_kernel(unsigned* __restrict__ o0, unsigned* __restrict__ o1,
                                  unsigned* __restrict__ bs) {
    __shared__ unsigned sh[256];
    int t = threadIdx.x, b = blockIdx.x;
    unsigned* off = (b < NBLK) ? o0 : o1;
    int bb = (b < NBLK) ? b : b - NBLK;
    unsigned v = off[bb*256 + t];
    sh[t] = v; __syncthreads();
    for (int st = 1; st < 256; st <<= 1) {
        unsigned a = (t >= st) ? sh[t-st] : 0u;
        __syncthreads();
        sh[t] += a;
        __syncthreads();
    }
    off[bb*256 + t] = sh[t] - v;          // exclusive within block
    if (t == 255) bs[b] = sh[255];
}

// blocks 0,1: segment scans; block 2 (if do_tabs): per-dim constant tables
__global__ void scan2_dual_kernel(unsigned* __restrict__ bs_all,
                                  const float* __restrict__ Yw, const float* __restrict__ Xw,
                                  float4* __restrict__ wtab, float4* __restrict__ xtab0,
                                  float4* __restrict__ xtab1, int do_tabs) {
    if (blockIdx.x == 2) {
        if (!do_tabs) return;
        int d = threadIdx.x;
        if (d >= DD) return;
        float s, c, Yd = Yw[d];
        sincosf(-Yd, &s, &c);
        float sst, cst;
        sincosf(Yd * 0.125f, &sst, &cst);
        wtab[d] = make_float4(c, s, cst, sst);
        float th = Xw[d] * 0.125f;
        float s1, c1, s8, c8, s9, c9;
        sincosf(th, &s1, &c1);
        sincosf(8.f*th, &s8, &c8);
        sincosf(9.f*th, &s9, &c9);
        xtab0[d] = make_float4(c1, s1, c8, -s8);
        xtab1[d] = make_float4(c9, s9, 0.f, 0.f);
        return;
    }
    __shared__ unsigned sh[256];
    __shared__ unsigned carry;
    unsigned* bs = bs_all + blockIdx.x*NBLK;
    int t = threadIdx.x;
    if (t == 0) carry = 0u;
    __syncthreads();
    for (int base = 0; base < NBLK; base += 256) {
        int i = base + t;
        unsigned v = (i < NBLK) ? bs[i] : 0u;
        sh[t] = v; __syncthreads();
        for (int st = 1; st < 256; st <<= 1) {
            unsigned a = (t >= st) ? sh[t-st] : 0u;
            __syncthreads();
            sh[t] += a;
            __syncthreads();
        }
        unsigned tot = sh[255];
        if (i < NBLK) bs[i] = (sh[t] - v) + carry;
        __syncthreads();
        if (t == 0) carry += tot;
        __syncthreads();
    }
}

__global__ void scan3_dual_kernel(unsigned* __restrict__ o0, unsigned* __restrict__ o1,
                                  const unsigned* __restrict__ bs) {
    int b = blockIdx.x;
    unsigned* off = (b < NBLK) ? o0 : o1;
    int bb = (b < NBLK) ? b : b - NBLK;
    off[bb*256 + threadIdx.x] += bs[b];
}

// leaves off[pix] = END of bucket; start = pix ? off[pix-1] : 0
// main path: only tss needed (xs consumed solely by the fallback)
__global__ void sort_t_kernel(const int* __restrict__ ey, const int* __restrict__ ex,
                              const float* __restrict__ t, unsigned* __restrict__ off,
                              float* __restrict__ tss, int N) {
    int e = blockIdx.x*blockDim.x + threadIdx.x;
    if (e >= N) return;
    int pix = ey[e]*WW + ex[e];
    unsigned pos = atomicAdd(&off[pix], 1u);
    tss[pos] = t[e];
}

// fallback path: tss + xs
__global__ void sort_kernel(const int* __restrict__ ey, const int* __restrict__ ex,
                            const float* __restrict__ t, unsigned* __restrict__ off,
                            float* __restrict__ tss, int* __restrict__ xs, int N) {
    int e = blockIdx.x*blockDim.x + threadIdx.x;
    if (e >= N) return;
    int pix = ey[e]*WW + ex[e];
    unsigned pos = atomicAdd(&off[pix], 1u);
    tss[pos] = t[e];
    xs[pos]  = ex[e];
}

// slim query pixel-sort: scatter only (window count folded into query_sep, v16)
__global__ void qsort_kernel(const int* __restrict__ qy, const int* __restrict__ qx,
                             unsigned* __restrict__ qoff, unsigned* __restrict__ qidx, int M) {
    int q = blockIdx.x*blockDim.x + threadIdx.x;
    if (q >= M) return;
    int pix = qy[q]*WW + qx[q];
    unsigned pos = atomicAdd(&qoff[pix], 1u);
    qidx[pos] = q;
}

// ================= fused build+convh: sliding-DFT row sweep (validated v14 form) =============
// H[hrow][x][dd] (packed half2) for image row hy = rb0 + hrow (zero outside image).
// Recurrence (fp32 internal): H[x+1] = e^{-i th} (H[x] - e^{-8i th} G[x-8] + e^{9i th} G[x+9])
__global__ __launch_bounds__(128) void rowsweep_kernel(
        const unsigned* __restrict__ off, const float* __restrict__ tss,
        const float* __restrict__ Tw, const float4* __restrict__ xtab0,
        const float4* __restrict__ xtab1, __half2* __restrict__ Hout, int rb0) {
    __shared__ __half2 ring[KK][DD];   // 17-deep G history, packed (gr,gi)
    int dd   = threadIdx.x;
    int hrow = blockIdx.y;
    int hy   = rb0 + hrow;
    int x0   = blockIdx.x * TS;
    int x1   = x0 + TS; if (x1 > WW) x1 = WW;
    __half2* hp = Hout + (long long)hrow*WW*DD + dd;

    if ((unsigned)hy >= HH) {                       // zero-pad rows
        __half2 z = __floats2half2_rn(0.f, 0.f);
        for (int x = x0; x < x1; ++x) hp[(long long)x*DD] = z;
        return;
    }

    float Td = Tw[dd];
    float4 t0 = xtab0[dd], t1 = xtab1[dd];
    const float er_ = t0.x,  ei_ = t0.y;    // e^{+i th}  (init weight step)
    const float ar  = t0.x,  ai  = -t0.y;   // e^{-i th}  (recurrence rotation)
    const float w0r = t0.z,  w0i = t0.w;    // e^{-8 i th}
    const float w17r = t1.x, w17i = t1.y;   // e^{+9 i th}

    const int rowbase = hy*WW;
    const unsigned* offr = off + rowbase;

#define GAT(col, gr, gi)                                                    \
    {                                                                       \
        gr = 0.f; gi = 0.f;                                                 \
        if ((unsigned)(col) < WW) {                                         \
            int pix_ = rowbase + (col);                                     \
            unsigned st_ = pix_ ? off[pix_-1] : 0u;                         \
            unsigned en_ = offr[(col)];                                     \
            for (unsigned p_ = st_; p_ < en_; ++p_) {                       \
                float ss_, cc_;                                             \
                __sincosf(tss[p_]*Td, &ss_, &cc_);                          \
                gr += cc_; gi += ss_;                                       \
            }                                                               \
        }                                                                   \
    }

    // init: H[x0] direct 17-tap, fill ring with G[x0-8 .. x0+8]
    float hr = 0.f, hi = 0.f;
    float wr = w0r, wi = w0i;
    #pragma unroll
    for (int j = 0; j < KK; ++j) {
        float gr, gi; GAT(x0 + j - RAD, gr, gi);
        hr = fmaf(gr, wr, hr); hr = fmaf(-gi, wi, hr);
        hi = fmaf(gr, wi, hi); hi = fmaf(gi, wr, hi);
        ring[j][dd] = __floats2half2_rn(gr, gi);
        float nr = wr*er_ - wi*ei_;
        wi       = wr*ei_ + wi*er_;
        wr       = nr;
    }
    hp[(long long)x0*DD] = __floats2half2_rn(hr, hi);

    int ri = 0;
    for (int xn = x0 + 1; xn < x1; ++xn) {
        float gr, gi; GAT(xn + RAD, gr, gi);            // G[xn+8] (new)
        float2 go = __half22float2(ring[ri][dd]);       // G[xn-9] (old)
        ring[ri][dd] = __floats2half2_rn(gr, gi);
        ri = (ri + 1 == KK) ? 0 : ri + 1;
        float tr = hr - (go.x*w0r - go.y*w0i) + (gr*w17r - gi*w17i);
        float ti = hi - (go.x*w0i + go.y*w0r) + (gr*w17i + gi*w17r);
        hr = tr*ar - ti*ai;
        hi = tr*ai + ti*ar;
        hp[(long long)xn*DD] = __floats2half2_rn(hr, hi);
    }
#undef GAT
}

// ================= stage 2: 17-tap vertical gather; in-wave window count (v16) ================
__global__ __launch_bounds__(256) void query_sep_kernel(
        const unsigned* __restrict__ qidx, const int* __restrict__ qy,
        const int* __restrict__ qx, const float* __restrict__ qt,
        const float* __restrict__ Tw, const float4* __restrict__ wtab,
        const unsigned* __restrict__ H, const unsigned* __restrict__ off,
        float* __restrict__ out, int M, int r0, int band, int rb0,
        long long out_n, int real_only) {
    int lt   = threadIdx.x;
    int p    = blockIdx.x*4 + (lt >> 6);
    int lane = lt & 63;
    if (p >= M) return;
    int q = (int)qidx[p];
    int cy = qy[q];
    if (cy < r0 || cy >= r0 + band) return;
    int cx = qx[q];
    int d0 = lane*2, d1 = d0 + 1;

    // ---- in-wave window count: lanes 0..16 each handle one row (off is post-sort: END) ----
    unsigned part = 0;
    if (lane < KK) {
        int yy = cy + lane - RAD;
        if ((unsigned)yy < HH) {
            int xlo = cx - RAD; if (xlo < 0) xlo = 0;
            int xhi = cx + RAD; if (xhi > WW-1) xhi = WW-1;
            int plo = yy*WW + xlo, phi = yy*WW + xhi;
            unsigned st = plo ? off[plo-1] : 0u;
            part = off[phi] - st;
        }
    }
    for (int o = 32; o; o >>= 1) part += __shfl_down(part, o);
    float cnt = (float)__shfl(part, 0);

    float4 w0 = wtab[d0], w1 = wtab[d1];
    float wyr0 = w0.x, wyi0 = w0.y, cst0 = w0.z, sst0 = w0.w;
    float wyr1 = w1.x, wyi1 = w1.y, cst1 = w1.z, sst1 = w1.w;

    const unsigned* hp = H + ((long long)(cy - RAD - rb0)*WW + cx)*DD + d0;
    float er0 = 0.f, ei0 = 0.f, er1 = 0.f, ei1 = 0.f;
    #pragma unroll
    for (int i = 0; i < KK; ++i) {
        uint2 v = *(const uint2*)(hp + (long long)i*WW*DD);
        float2 f0 = __half22float2(*(const __half2*)&v.x);
        float2 f1 = __half22float2(*(const __half2*)&v.y);
        er0 = fmaf(f0.x, wyr0, er0); er0 = fmaf(-f0.y, wyi0, er0);
        ei0 = fmaf(f0.x, wyi0, ei0); ei0 = fmaf(f0.y, wyr0, ei0);
        er1 = fmaf(f1.x, wyr1, er1); er1 = fmaf(-f1.y, wyi1, er1);
        ei1 = fmaf(f1.x, wyi1, ei1); ei1 = fmaf(f1.y, wyr1, ei1);
        float nr;
        nr = wyr0*cst0 - wyi0*sst0; wyi0 = wyr0*sst0 + wyi0*cst0; wyr0 = nr;
        nr = wyr1*cst1 - wyi1*sst1; wyi1 = wyr1*sst1 + wyi1*cst1; wyr1 = nr;
    }

    float inv = 1.0f / fmaxf(cnt, 1.0f);
    float s, c, qtv = qt[q];
    __sincosf(qtv * Tw[d0], &s, &c);
    float outr0 = (er0*c + ei0*s) * inv, outi0 = (ei0*c - er0*s) * inv;
    __sincosf(qtv * Tw[d1], &s, &c);
    float outr1 = (er1*c + ei1*s) * inv, outi1 = (ei1*c - er1*s) * inv;

    long long base = (long long)q*DD + d0;
    if (real_only) {
        if (base + 1 < out_n) *(float2*)(out + base) = make_float2(outr0, outr1);
        else if (base < out_n) out[base] = outr0;
    } else if (2*base + 3 < out_n) {
        *(float4*)(out + 2*base) = make_float4(outr0, outi0, outr1, outi1);
    }
}

// ================= fallback: event-direct query (validated v4, 2.69 ms) =================
__global__ __launch_bounds__(256) void query_direct_kernel(
        const int* __restrict__ qy, const int* __restrict__ qx,
        const float* __restrict__ qt, const float* __restrict__ Tw,
        const float* __restrict__ Xw, const float* __restrict__ Yw,
        const unsigned* __restrict__ off, const float* __restrict__ tss,
        const int* __restrict__ xs, float* __restrict__ out,
        int M, long long out_n, int real_only) {
    __shared__ float2 swx[KK*DD];
    __shared__ float2 swy[KK*DD];
    int lt = threadIdx.x;
    for (int idx = lt; idx < KK*DD; idx += 256) {
        int j = idx / DD, dd = idx & (DD-1);
        float s, c;
        sincosf((float)(j - RAD) * 0.125f * Xw[dd], &s, &c);
        swx[idx] = make_float2(c, s);
        sincosf((float)(j - RAD) * 0.125f * Yw[dd], &s, &c);
        swy[idx] = make_float2(c, s);
    }
    __syncthreads();

    int q = blockIdx.x*2 + (lt >> 7);
    int d = lt & (DD-1);
    if (q >= M) return;

    int cy = qy[q], cx = qx[q];
    float Td = Tw[d];
    int xlo = cx - RAD; if (xlo < 0) xlo = 0;
    int xhi = cx + RAD; if (xhi > WW-1) xhi = WW-1;

    float accr = 0.f, acci = 0.f;
    unsigned cnt = 0;
    for (int i = 0; i < KK; ++i) {
        int yy = cy + i - RAD;
        if ((unsigned)yy >= HH) continue;
        int plo = yy*WW + xlo, phi = yy*WW + xhi;
        unsigned st = plo ? off[plo-1] : 0u;
        unsigned en = off[phi];
        cnt += en - st;
        float rr = 0.f, ri = 0.f;
        for (unsigned p = st; p < en; ++p) {
            float te = tss[p];
            int   xe = xs[p];
            float2 wx = swx[(xe - cx + RAD)*DD + d];
            float s, c;
            __sincosf(te * Td, &s, &c);
            rr = fmaf(c, wx.x, rr); rr = fmaf(-s, wx.y, rr);
            ri = fmaf(c, wx.y, ri); ri = fmaf(s, wx.x, ri);
        }
        float2 wy = swy[i*DD + d];
        accr = fmaf(rr, wy.x, accr); accr = fmaf(-ri, wy.y, accr);
        acci = fmaf(rr, wy.y, acci); acci = fmaf(ri, wy.x, acci);
    }

    float s, c;
    sincosf(qt[q] * Td, &s, &c);
    float inv = 1.0f / fmaxf((float)cnt, 1.0f);
    float outr = (accr*c + acci*s) * inv;
    float outi = (acci*c - accr*s) * inv;
    long long base = (long long)q*DD + d;
    if (real_only) { if (base < out_n) out[base] = outr; }
    else if (2*base + 1 < out_n) { out[2*base] = outr; out[2*base+1] = outi; }
}

extern "C" void kernel_launch(void* const* d_in, const int* in_sizes, int n_in,
                              void* d_out, int out_size, void* d_ws, size_t ws_size,
                              hipStream_t stream) {
    const float* t  = (const float*)d_in[0];
    const int*   ey = (const int*)d_in[1];
    const int*   ex = (const int*)d_in[2];
    const int*   qy = (const int*)d_in[3];
    const int*   qx = (const int*)d_in[4];
    const float* qt = (const float*)d_in[5];
    const float* Tw = (const float*)d_in[6];
    const float* Xw = (const float*)d_in[7];
    const float* Yw = (const float*)d_in[8];

    int N = in_sizes[0];
    int M = in_sizes[3];

    // ws: [off | qoff | bs(2 segs) | tss | xs | qidx | wtab | xtab0 | xtab1 | H band]
    size_t off_b  = al256((size_t)HWPIX*4);
    size_t qoff_b = al256((size_t)HWPIX*4);
    size_t bs_b   = al256((size_t)2*NBLK*4);
    size_t tss_b  = al256((size_t)N*4);
    size_t xs_b   = al256((size_t)N*4);
    size_t qidx_b = al256((size_t)M*4);
    size_t wt_b   = al256((size_t)DD*16);
    size_t xt_b   = al256((size_t)DD*16);
    size_t fixed  = off_b + qoff_b + bs_b + tss_b + xs_b + qidx_b + wt_b + 2*xt_b;
    size_t need_min = off_b + qoff_b + bs_b + tss_b + xs_b;

    if (ws_size < need_min || d_ws == nullptr) {
        hipMemsetAsync(d_out, 0, (size_t)out_size*4, stream);   // safe diagnostic
        return;
    }

    char*     ws   = (char*)d_ws;
    unsigned* off  = (unsigned*)ws;
    unsigned* qoff = (unsigned*)(ws + off_b);
    unsigned* bs   = (unsigned*)(ws + off_b + qoff_b);
    float*    tss  = (float*)(ws + off_b + qoff_b + bs_b);
    int*      xs   = (int*)(ws + off_b + qoff_b + bs_b + tss_b);
    unsigned* qidx = (unsigned*)(ws + off_b + qoff_b + bs_b + tss_b + xs_b);
    float4*   wtab = (float4*)(ws + off_b + qoff_b + bs_b + tss_b + xs_b + qidx_b);
    float4*   xtab0= (float4*)(ws + off_b + qoff_b + bs_b + tss_b + xs_b + qidx_b + wt_b);
    float4*   xtab1= (float4*)(ws + off_b + qoff_b + bs_b + tss_b + xs_b + qidx_b + wt_b + xt_b);
    __half2*  H    = (__half2*)(ws + fixed);

    long long full = (long long)M * DD;
    int real_only = (out_size < 2*full) ? 1 : 0;

    // ---- band sizing first (host arithmetic): decides which sort variant we need ----
    long long band_sz = 0;
    if (ws_size > fixed) {
        long long hrows_fit = (long long)((ws_size - fixed) / ((size_t)WW*DD*4));
        band_sz = hrows_fit - 16;
        if (band_sz > HH) band_sz = HH;
    }
    int do_tabs = (band_sz >= 32) ? 1 : 0;

    // ---- batched event+query counting sort (off and qoff adjacent: one memset) ----
    hipMemsetAsync(off, 0, off_b + (size_t)HWPIX*4, stream);
    int hb = ((N > M ? N : M) + 255)/256;
    hist_dual_kernel<<<dim3(hb, 2), 256, 0, stream>>>(ey, ex, N, qy, qx, M, off, qoff);
    scan1_dual_kernel<<<2*NBLK, 256, 0, stream>>>(off, qoff, bs);
    scan2_dual_kernel<<<3, 256, 0, stream>>>(bs, Yw, Xw, wtab, xtab0, xtab1, do_tabs);
    scan3_dual_kernel<<<2*NBLK, 256, 0, stream>>>(off, qoff, bs);

    if (!do_tabs) {
        // fallback needs xs too
        sort_kernel<<<(N+255)/256, 256, 0, stream>>>(ey, ex, t, off, tss, xs, N);
        query_direct_kernel<<<(M+1)/2, 256, 0, stream>>>(
            qy, qx, qt, Tw, Xw, Yw, off, tss, xs, (float*)d_out,
            M, (long long)out_size, real_only);
        return;
    }

    // main path: tss-only sort (xs unused downstream)
    sort_t_kernel<<<(N+255)/256, 256, 0, stream>>>(ey, ex, t, off, tss, N);

    // query pixel-sort (slim scatter; count folded into query_sep)
    qsort_kernel<<<(M+255)/256, 256, 0, stream>>>(qy, qx, qoff, qidx, M);

    // ---- banded sweep + gather ----
    for (int r0 = 0; r0 < HH; r0 += (int)band_sz) {
        int band  = (HH - r0 < band_sz) ? (HH - r0) : (int)band_sz;
        int hrows = band + 16;
        dim3 g(XT, hrows);
        rowsweep_kernel<<<g, 128, 0, stream>>>(off, tss, Tw, xtab0, xtab1, H, r0 - RAD);
        query_sep_kernel<<<(M+3)/4, 256, 0, stream>>>(
            qidx, qy, qx, qt, Tw, wtab, (const unsigned*)H, off, (float*)d_out,
            M, r0, band, r0 - RAD, (long long)out_size, real_only);
    }
}

// Round 21
// 209.257 us; speedup vs baseline: 1.1944x; 1.0033x over previous
//
#include <hip/hip_runtime.h>
#include <hip/hip_fp16.h>
#include <math.h>

#define HH 480
#define WW 640
#define RAD 8
#define KK 17
#define DD 128
#define HWPIX (HH*WW)       // 307200
#define NBLK (HWPIX/256)    // 1200 exactly
#define TS 40               // x-tile width in rowsweep (v21: 80->40 for 2x TLP)
#define XT 16               // tiles per row (XT*TS == WW)

static inline size_t al256(size_t x){ return (x + 255) & ~(size_t)255; }

// ================= batched counting-sort machinery (events + queries, validated v10/v12) ======
__global__ void hist_dual_kernel(const int* __restrict__ ey, const int* __restrict__ ex, int N,
                                 const int* __restrict__ qy, const int* __restrict__ qx, int M,
                                 unsigned* __restrict__ off, unsigned* __restrict__ qoff) {
    int e = blockIdx.x*blockDim.x + threadIdx.x;
    if (blockIdx.y == 0) {
        if (e < N) atomicAdd(&off[ey[e]*WW + ex[e]], 1u);
    } else {
        if (e < M) atomicAdd(&qoff[qy[e]*WW + qx[e]], 1u);
    }
}

__global__ void scan1_dual_kernel(unsigned* __restrict__ o0, unsigned* __restrict__ o1,
                                  unsigned* __restrict__ bs) {
    __shared__ unsigned sh[256];
    int t = threadIdx.x, b = blockIdx.x;
    unsigned* off = (b < NBLK) ? o0 : o1;
    int bb = (b < NBLK) ? b : b - NBLK;
    unsigned v = off[bb*256 + t];
    sh[t] = v; __syncthreads();
    for (int st = 1; st < 256; st <<= 1) {
        unsigned a = (t >= st) ? sh[t-st] : 0u;
        __syncthreads();
        sh[t] += a;
        __syncthreads();
    }
    off[bb*256 + t] = sh[t] - v;          // exclusive within block
    if (t == 255) bs[b] = sh[255];
}

// blocks 0,1: segment scans; block 2 (if do_tabs): per-dim constant tables
__global__ void scan2_dual_kernel(unsigned* __restrict__ bs_all,
                                  const float* __restrict__ Yw, const float* __restrict__ Xw,
                                  float4* __restrict__ wtab, float4* __restrict__ xtab0,
                                  float4* __restrict__ xtab1, int do_tabs) {
    if (blockIdx.x == 2) {
        if (!do_tabs) return;
        int d = threadIdx.x;
        if (d >= DD) return;
        float s, c, Yd = Yw[d];
        sincosf(-Yd, &s, &c);
        float sst, cst;
        sincosf(Yd * 0.125f, &sst, &cst);
        wtab[d] = make_float4(c, s, cst, sst);
        float th = Xw[d] * 0.125f;
        float s1, c1, s8, c8, s9, c9;
        sincosf(th, &s1, &c1);
        sincosf(8.f*th, &s8, &c8);
        sincosf(9.f*th, &s9, &c9);
        xtab0[d] = make_float4(c1, s1, c8, -s8);
        xtab1[d] = make_float4(c9, s9, 0.f, 0.f);
        return;
    }
    __shared__ unsigned sh[256];
    __shared__ unsigned carry;
    unsigned* bs = bs_all + blockIdx.x*NBLK;
    int t = threadIdx.x;
    if (t == 0) carry = 0u;
    __syncthreads();
    for (int base = 0; base < NBLK; base += 256) {
        int i = base + t;
        unsigned v = (i < NBLK) ? bs[i] : 0u;
        sh[t] = v; __syncthreads();
        for (int st = 1; st < 256; st <<= 1) {
            unsigned a = (t >= st) ? sh[t-st] : 0u;
            __syncthreads();
            sh[t] += a;
            __syncthreads();
        }
        unsigned tot = sh[255];
        if (i < NBLK) bs[i] = (sh[t] - v) + carry;
        __syncthreads();
        if (t == 0) carry += tot;
        __syncthreads();
    }
}

__global__ void scan3_dual_kernel(unsigned* __restrict__ o0, unsigned* __restrict__ o1,
                                  const unsigned* __restrict__ bs) {
    int b = blockIdx.x;
    unsigned* off = (b < NBLK) ? o0 : o1;
    int bb = (b < NBLK) ? b : b - NBLK;
    off[bb*256 + threadIdx.x] += bs[b];
}

// leaves off[pix] = END of bucket; start = pix ? off[pix-1] : 0
// main path: only tss needed (xs consumed solely by the fallback)
__global__ void sort_t_kernel(const int* __restrict__ ey, const int* __restrict__ ex,
                              const float* __restrict__ t, unsigned* __restrict__ off,
                              float* __restrict__ tss, int N) {
    int e = blockIdx.x*blockDim.x + threadIdx.x;
    if (e >= N) return;
    int pix = ey[e]*WW + ex[e];
    unsigned pos = atomicAdd(&off[pix], 1u);
    tss[pos] = t[e];
}

// fallback path: tss + xs
__global__ void sort_kernel(const int* __restrict__ ey, const int* __restrict__ ex,
                            const float* __restrict__ t, unsigned* __restrict__ off,
                            float* __restrict__ tss, int* __restrict__ xs, int N) {
    int e = blockIdx.x*blockDim.x + threadIdx.x;
    if (e >= N) return;
    int pix = ey[e]*WW + ex[e];
    unsigned pos = atomicAdd(&off[pix], 1u);
    tss[pos] = t[e];
    xs[pos]  = ex[e];
}

// slim query pixel-sort: scatter only (window count folded into query_sep, v16)
__global__ void qsort_kernel(const int* __restrict__ qy, const int* __restrict__ qx,
                             unsigned* __restrict__ qoff, unsigned* __restrict__ qidx, int M) {
    int q = blockIdx.x*blockDim.x + threadIdx.x;
    if (q >= M) return;
    int pix = qy[q]*WW + qx[q];
    unsigned pos = atomicAdd(&qoff[pix], 1u);
    qidx[pos] = q;
}

// ================= fused build+convh: sliding-DFT row sweep (validated v14 form) =============
// H[hrow][x][dd] (packed half2) for image row hy = rb0 + hrow (zero outside image).
// Recurrence (fp32 internal): H[x+1] = e^{-i th} (H[x] - e^{-8i th} G[x-8] + e^{9i th} G[x+9])
__global__ __launch_bounds__(128) void rowsweep_kernel(
        const unsigned* __restrict__ off, const float* __restrict__ tss,
        const float* __restrict__ Tw, const float4* __restrict__ xtab0,
        const float4* __restrict__ xtab1, __half2* __restrict__ Hout, int rb0) {
    __shared__ __half2 ring[KK][DD];   // 17-deep G history, packed (gr,gi)
    int dd   = threadIdx.x;
    int hrow = blockIdx.y;
    int hy   = rb0 + hrow;
    int x0   = blockIdx.x * TS;
    int x1   = x0 + TS; if (x1 > WW) x1 = WW;
    __half2* hp = Hout + (long long)hrow*WW*DD + dd;

    if ((unsigned)hy >= HH) {                       // zero-pad rows
        __half2 z = __floats2half2_rn(0.f, 0.f);
        for (int x = x0; x < x1; ++x) hp[(long long)x*DD] = z;
        return;
    }

    float Td = Tw[dd];
    float4 t0 = xtab0[dd], t1 = xtab1[dd];
    const float er_ = t0.x,  ei_ = t0.y;    // e^{+i th}  (init weight step)
    const float ar  = t0.x,  ai  = -t0.y;   // e^{-i th}  (recurrence rotation)
    const float w0r = t0.z,  w0i = t0.w;    // e^{-8 i th}
    const float w17r = t1.x, w17i = t1.y;   // e^{+9 i th}

    const int rowbase = hy*WW;
    const unsigned* offr = off + rowbase;

#define GAT(col, gr, gi)                                                    \
    {                                                                       \
        gr = 0.f; gi = 0.f;                                                 \
        if ((unsigned)(col) < WW) {                                         \
            int pix_ = rowbase + (col);                                     \
            unsigned st_ = pix_ ? off[pix_-1] : 0u;                         \
            unsigned en_ = offr[(col)];                                     \
            for (unsigned p_ = st_; p_ < en_; ++p_) {                       \
                float ss_, cc_;                                             \
                __sincosf(tss[p_]*Td, &ss_, &cc_);                          \
                gr += cc_; gi += ss_;                                       \
            }                                                               \
        }                                                                   \
    }

    // init: H[x0] direct 17-tap, fill ring with G[x0-8 .. x0+8]
    float hr = 0.f, hi = 0.f;
    float wr = w0r, wi = w0i;
    #pragma unroll
    for (int j = 0; j < KK; ++j) {
        float gr, gi; GAT(x0 + j - RAD, gr, gi);
        hr = fmaf(gr, wr, hr); hr = fmaf(-gi, wi, hr);
        hi = fmaf(gr, wi, hi); hi = fmaf(gi, wr, hi);
        ring[j][dd] = __floats2half2_rn(gr, gi);
        float nr = wr*er_ - wi*ei_;
        wi       = wr*ei_ + wi*er_;
        wr       = nr;
    }
    hp[(long long)x0*DD] = __floats2half2_rn(hr, hi);

    int ri = 0;
    for (int xn = x0 + 1; xn < x1; ++xn) {
        float gr, gi; GAT(xn + RAD, gr, gi);            // G[xn+8] (new)
        float2 go = __half22float2(ring[ri][dd]);       // G[xn-9] (old)
        ring[ri][dd] = __floats2half2_rn(gr, gi);
        ri = (ri + 1 == KK) ? 0 : ri + 1;
        float tr = hr - (go.x*w0r - go.y*w0i) + (gr*w17r - gi*w17i);
        float ti = hi - (go.x*w0i + go.y*w0r) + (gr*w17i + gi*w17r);
        hr = tr*ar - ti*ai;
        hi = tr*ai + ti*ar;
        hp[(long long)xn*DD] = __floats2half2_rn(hr, hi);
    }
#undef GAT
}

// ================= stage 2: 17-tap vertical gather; in-wave window count (v16) ================
__global__ __launch_bounds__(256) void query_sep_kernel(
        const unsigned* __restrict__ qidx, const int* __restrict__ qy,
        const int* __restrict__ qx, const float* __restrict__ qt,
        const float* __restrict__ Tw, const float4* __restrict__ wtab,
        const unsigned* __restrict__ H, const unsigned* __restrict__ off,
        float* __restrict__ out, int M, int r0, int band, int rb0,
        long long out_n, int real_only) {
    int lt   = threadIdx.x;
    int p    = blockIdx.x*4 + (lt >> 6);
    int lane = lt & 63;
    if (p >= M) return;
    int q = (int)qidx[p];
    int cy = qy[q];
    if (cy < r0 || cy >= r0 + band) return;
    int cx = qx[q];
    int d0 = lane*2, d1 = d0 + 1;

    // ---- in-wave window count: lanes 0..16 each handle one row (off is post-sort: END) ----
    unsigned part = 0;
    if (lane < KK) {
        int yy = cy + lane - RAD;
        if ((unsigned)yy < HH) {
            int xlo = cx - RAD; if (xlo < 0) xlo = 0;
            int xhi = cx + RAD; if (xhi > WW-1) xhi = WW-1;
            int plo = yy*WW + xlo, phi = yy*WW + xhi;
            unsigned st = plo ? off[plo-1] : 0u;
            part = off[phi] - st;
        }
    }
    for (int o = 32; o; o >>= 1) part += __shfl_down(part, o);
    float cnt = (float)__shfl(part, 0);

    float4 w0 = wtab[d0], w1 = wtab[d1];
    float wyr0 = w0.x, wyi0 = w0.y, cst0 = w0.z, sst0 = w0.w;
    float wyr1 = w1.x, wyi1 = w1.y, cst1 = w1.z, sst1 = w1.w;

    const unsigned* hp = H + ((long long)(cy - RAD - rb0)*WW + cx)*DD + d0;
    float er0 = 0.f, ei0 = 0.f, er1 = 0.f, ei1 = 0.f;
    #pragma unroll
    for (int i = 0; i < KK; ++i) {
        uint2 v = *(const uint2*)(hp + (long long)i*WW*DD);
        float2 f0 = __half22float2(*(const __half2*)&v.x);
        float2 f1 = __half22float2(*(const __half2*)&v.y);
        er0 = fmaf(f0.x, wyr0, er0); er0 = fmaf(-f0.y, wyi0, er0);
        ei0 = fmaf(f0.x, wyi0, ei0); ei0 = fmaf(f0.y, wyr0, ei0);
        er1 = fmaf(f1.x, wyr1, er1); er1 = fmaf(-f1.y, wyi1, er1);
        ei1 = fmaf(f1.x, wyi1, ei1); ei1 = fmaf(f1.y, wyr1, ei1);
        float nr;
        nr = wyr0*cst0 - wyi0*sst0; wyi0 = wyr0*sst0 + wyi0*cst0; wyr0 = nr;
        nr = wyr1*cst1 - wyi1*sst1; wyi1 = wyr1*sst1 + wyi1*cst1; wyr1 = nr;
    }

    float inv = 1.0f / fmaxf(cnt, 1.0f);
    float s, c, qtv = qt[q];
    __sincosf(qtv * Tw[d0], &s, &c);
    float outr0 = (er0*c + ei0*s) * inv, outi0 = (ei0*c - er0*s) * inv;
    __sincosf(qtv * Tw[d1], &s, &c);
    float outr1 = (er1*c + ei1*s) * inv, outi1 = (ei1*c - er1*s) * inv;

    long long base = (long long)q*DD + d0;
    if (real_only) {
        if (base + 1 < out_n) *(float2*)(out + base) = make_float2(outr0, outr1);
        else if (base < out_n) out[base] = outr0;
    } else if (2*base + 3 < out_n) {
        *(float4*)(out + 2*base) = make_float4(outr0, outi0, outr1, outi1);
    }
}

// ================= fallback: event-direct query (validated v4, 2.69 ms) =================
__global__ __launch_bounds__(256) void query_direct_kernel(
        const int* __restrict__ qy, const int* __restrict__ qx,
        const float* __restrict__ qt, const float* __restrict__ Tw,
        const float* __restrict__ Xw, const float* __restrict__ Yw,
        const unsigned* __restrict__ off, const float* __restrict__ tss,
        const int* __restrict__ xs, float* __restrict__ out,
        int M, long long out_n, int real_only) {
    __shared__ float2 swx[KK*DD];
    __shared__ float2 swy[KK*DD];
    int lt = threadIdx.x;
    for (int idx = lt; idx < KK*DD; idx += 256) {
        int j = idx / DD, dd = idx & (DD-1);
        float s, c;
        sincosf((float)(j - RAD) * 0.125f * Xw[dd], &s, &c);
        swx[idx] = make_float2(c, s);
        sincosf((float)(j - RAD) * 0.125f * Yw[dd], &s, &c);
        swy[idx] = make_float2(c, s);
    }
    __syncthreads();

    int q = blockIdx.x*2 + (lt >> 7);
    int d = lt & (DD-1);
    if (q >= M) return;

    int cy = qy[q], cx = qx[q];
    float Td = Tw[d];
    int xlo = cx - RAD; if (xlo < 0) xlo = 0;
    int xhi = cx + RAD; if (xhi > WW-1) xhi = WW-1;

    float accr = 0.f, acci = 0.f;
    unsigned cnt = 0;
    for (int i = 0; i < KK; ++i) {
        int yy = cy + i - RAD;
        if ((unsigned)yy >= HH) continue;
        int plo = yy*WW + xlo, phi = yy*WW + xhi;
        unsigned st = plo ? off[plo-1] : 0u;
        unsigned en = off[phi];
        cnt += en - st;
        float rr = 0.f, ri = 0.f;
        for (unsigned p = st; p < en; ++p) {
            float te = tss[p];
            int   xe = xs[p];
            float2 wx = swx[(xe - cx + RAD)*DD + d];
            float s, c;
            __sincosf(te * Td, &s, &c);
            rr = fmaf(c, wx.x, rr); rr = fmaf(-s, wx.y, rr);
            ri = fmaf(c, wx.y, ri); ri = fmaf(s, wx.x, ri);
        }
        float2 wy = swy[i*DD + d];
        accr = fmaf(rr, wy.x, accr); accr = fmaf(-ri, wy.y, accr);
        acci = fmaf(rr, wy.y, acci); acci = fmaf(ri, wy.x, acci);
    }

    float s, c;
    sincosf(qt[q] * Td, &s, &c);
    float inv = 1.0f / fmaxf((float)cnt, 1.0f);
    float outr = (accr*c + acci*s) * inv;
    float outi = (acci*c - accr*s) * inv;
    long long base = (long long)q*DD + d;
    if (real_only) { if (base < out_n) out[base] = outr; }
    else if (2*base + 1 < out_n) { out[2*base] = outr; out[2*base+1] = outi; }
}

extern "C" void kernel_launch(void* const* d_in, const int* in_sizes, int n_in,
                              void* d_out, int out_size, void* d_ws, size_t ws_size,
                              hipStream_t stream) {
    const float* t  = (const float*)d_in[0];
    const int*   ey = (const int*)d_in[1];
    const int*   ex = (const int*)d_in[2];
    const int*   qy = (const int*)d_in[3];
    const int*   qx = (const int*)d_in[4];
    const float* qt = (const float*)d_in[5];
    const float* Tw = (const float*)d_in[6];
    const float* Xw = (const float*)d_in[7];
    const float* Yw = (const float*)d_in[8];

    int N = in_sizes[0];
    int M = in_sizes[3];

    // ws: [off | qoff | bs(2 segs) | tss | xs | qidx | wtab | xtab0 | xtab1 | H band]
    size_t off_b  = al256((size_t)HWPIX*4);
    size_t qoff_b = al256((size_t)HWPIX*4);
    size_t bs_b   = al256((size_t)2*NBLK*4);
    size_t tss_b  = al256((size_t)N*4);
    size_t xs_b   = al256((size_t)N*4);
    size_t qidx_b = al256((size_t)M*4);
    size_t wt_b   = al256((size_t)DD*16);
    size_t xt_b   = al256((size_t)DD*16);
    size_t fixed  = off_b + qoff_b + bs_b + tss_b + xs_b + qidx_b + wt_b + 2*xt_b;
    size_t need_min = off_b + qoff_b + bs_b + tss_b + xs_b;

    if (ws_size < need_min || d_ws == nullptr) {
        hipMemsetAsync(d_out, 0, (size_t)out_size*4, stream);   // safe diagnostic
        return;
    }

    char*     ws   = (char*)d_ws;
    unsigned* off  = (unsigned*)ws;
    unsigned* qoff = (unsigned*)(ws + off_b);
    unsigned* bs   = (unsigned*)(ws + off_b + qoff_b);
    float*    tss  = (float*)(ws + off_b + qoff_b + bs_b);
    int*      xs   = (int*)(ws + off_b + qoff_b + bs_b + tss_b);
    unsigned* qidx = (unsigned*)(ws + off_b + qoff_b + bs_b + tss_b + xs_b);
    float4*   wtab = (float4*)(ws + off_b + qoff_b + bs_b + tss_b + xs_b + qidx_b);
    float4*   xtab0= (float4*)(ws + off_b + qoff_b + bs_b + tss_b + xs_b + qidx_b + wt_b);
    float4*   xtab1= (float4*)(ws + off_b + qoff_b + bs_b + tss_b + xs_b + qidx_b + wt_b + xt_b);
    __half2*  H    = (__half2*)(ws + fixed);

    long long full = (long long)M * DD;
    int real_only = (out_size < 2*full) ? 1 : 0;

    // ---- band sizing first (host arithmetic): decides which sort variant we need ----
    long long band_sz = 0;
    if (ws_size > fixed) {
        long long hrows_fit = (long long)((ws_size - fixed) / ((size_t)WW*DD*4));
        band_sz = hrows_fit - 16;
        if (band_sz > HH) band_sz = HH;
    }
    int do_tabs = (band_sz >= 32) ? 1 : 0;

    // ---- batched event+query counting sort (off and qoff adjacent: one memset) ----
    hipMemsetAsync(off, 0, off_b + (size_t)HWPIX*4, stream);
    int hb = ((N > M ? N : M) + 255)/256;
    hist_dual_kernel<<<dim3(hb, 2), 256, 0, stream>>>(ey, ex, N, qy, qx, M, off, qoff);
    scan1_dual_kernel<<<2*NBLK, 256, 0, stream>>>(off, qoff, bs);
    scan2_dual_kernel<<<3, 256, 0, stream>>>(bs, Yw, Xw, wtab, xtab0, xtab1, do_tabs);
    scan3_dual_kernel<<<2*NBLK, 256, 0, stream>>>(off, qoff, bs);

    if (!do_tabs) {
        // fallback needs xs too
        sort_kernel<<<(N+255)/256, 256, 0, stream>>>(ey, ex, t, off, tss, xs, N);
        query_direct_kernel<<<(M+1)/2, 256, 0, stream>>>(
            qy, qx, qt, Tw, Xw, Yw, off, tss, xs, (float*)d_out,
            M, (long long)out_size, real_only);
        return;
    }

    // main path: tss-only sort (xs unused downstream)
    sort_t_kernel<<<(N+255)/256, 256, 0, stream>>>(ey, ex, t, off, tss, N);

    // query pixel-sort (slim scatter; count folded into query_sep)
    qsort_kernel<<<(M+255)/256, 256, 0, stream>>>(qy, qx, qoff, qidx, M);

    // ---- banded sweep + gather ----
    for (int r0 = 0; r0 < HH; r0 += (int)band_sz) {
        int band  = (HH - r0 < band_sz) ? (HH - r0) : (int)band_sz;
        int hrows = band + 16;
        dim3 g(XT, hrows);
        rowsweep_kernel<<<g, 128, 0, stream>>>(off, tss, Tw, xtab0, xtab1, H, r0 - RAD);
        query_sep_kernel<<<(M+3)/4, 256, 0, stream>>>(
            qidx, qy, qx, qt, Tw, wtab, (const unsigned*)H, off, (float*)d_out,
            M, r0, band, r0 - RAD, (long long)out_size, real_only);
    }
}